// Round 1
// baseline (2154.903 us; speedup 1.0000x reference)
//
#include <hip/hip_runtime.h>
#include <hip/hip_bf16.h>

#define B_ 2
#define Q_ 1024
#define P_ 3072
#define HID_ 4096
#define H_ 32
#define KV_ 8
#define D_ 128
#define S_ 4096
#define NQKV 6144
#define SCALE 0.08838834764831845f

typedef __attribute__((ext_vector_type(4))) float f32x4;
typedef __attribute__((ext_vector_type(8))) unsigned short u16x8;
typedef __attribute__((ext_vector_type(4))) unsigned short u16x4;
typedef __attribute__((ext_vector_type(8))) __bf16 bf16x8;

__device__ __forceinline__ unsigned short f2bf(float f){
  unsigned u = __builtin_bit_cast(unsigned, f);
  unsigned r = (u + 0x7FFFu + ((u >> 16) & 1u)) >> 16;
  return (unsigned short)r;
}
__device__ __forceinline__ float bf2f(unsigned short h){
  unsigned u = ((unsigned)h) << 16;
  return __builtin_bit_cast(float, u);
}
__device__ __forceinline__ void f2hilo(float f, unsigned short& h, unsigned short& l){
  h = f2bf(f);
  l = f2bf(f - bf2f(h));
}
__device__ __forceinline__ f32x4 mfma16(u16x8 a, u16x8 b, f32x4 c){
  return __builtin_amdgcn_mfma_f32_16x16x32_bf16(
      __builtin_bit_cast(bf16x8, a), __builtin_bit_cast(bf16x8, b), c, 0, 0, 0);
}

// ---------------- cache convert: fp32 (B,KV,P,D) -> hi/lo bf16 at s in [0,P) -------------
__global__ __launch_bounds__(256) void cache_convert(
    const float* __restrict__ kc, const float* __restrict__ vc,
    unsigned short* __restrict__ Khi, unsigned short* __restrict__ Klo,
    unsigned short* __restrict__ Vb){
  const int PD = P_ * D_;
  const long SD = (long)S_ * D_;
  int total4 = (B_ * KV_ * PD) >> 2;
  for(int i4 = blockIdx.x * 256 + threadIdx.x; i4 < total4; i4 += gridDim.x * 256){
    long i = (long)i4 * 4;
    int bkv = (int)(i / PD);
    int rem = (int)(i - (long)bkv * PD);
    long dst = (long)bkv * SD + rem;
    float4 k4 = *(const float4*)(kc + i);
    float4 v4 = *(const float4*)(vc + i);
    unsigned short h0,h1,h2,h3,l0,l1,l2,l3;
    f2hilo(k4.x,h0,l0); f2hilo(k4.y,h1,l1); f2hilo(k4.z,h2,l2); f2hilo(k4.w,h3,l3);
    *(u16x4*)(Khi + dst) = (u16x4){h0,h1,h2,h3};
    *(u16x4*)(Klo + dst) = (u16x4){l0,l1,l2,l3};
    *(u16x4*)(Vb  + dst) = (u16x4){f2bf(v4.x), f2bf(v4.y), f2bf(v4.z), f2bf(v4.w)};
  }
}

// ---------------- GEMM: qkv projection, A fp32 2048x4096, B = [Wq|Wk|Wv] ----------------
#define AK 40  // padded LDS stride (32 + 8)
__global__ __launch_bounds__(256) void gemm_qkv(
    const float* __restrict__ A, const float* __restrict__ Wq,
    const float* __restrict__ Wk, const float* __restrict__ Wv,
    float* __restrict__ Craw){
  __shared__ __align__(16) unsigned short Ahi[128*AK], Alo[128*AK], Bhi[128*AK], Blo[128*AK];
  int tid = threadIdx.x;
  int m0 = blockIdx.y * 128, n0 = blockIdx.x * 128;
  const float* Wsrc; int ldb, c0;
  if(n0 < 4096){ Wsrc = Wq; ldb = 4096; c0 = n0; }
  else if(n0 < 5120){ Wsrc = Wk; ldb = 1024; c0 = n0 - 4096; }
  else { Wsrc = Wv; ldb = 1024; c0 = n0 - 5120; }
  int wid = tid >> 6, lane = tid & 63, lr = lane & 15, lg = lane >> 4;
  int wm = (wid >> 1) * 64, wn = (wid & 1) * 64;
  f32x4 zero = {0.f,0.f,0.f,0.f};
  f32x4 acc[4][4];
  for(int mi=0;mi<4;++mi) for(int ni=0;ni<4;++ni) acc[mi][ni] = zero;

  for(int kt = 0; kt < 128; ++kt){
    int k0 = kt * 32;
    __syncthreads();
    {
      int kk = (tid & 7) * 4;
      int rb = tid >> 3;
      #pragma unroll
      for(int r = 0; r < 4; ++r){
        int row = r * 32 + rb;
        float4 a = *(const float4*)(A + (long)(m0 + row) * 4096 + k0 + kk);
        unsigned short h0,h1,h2,h3,l0,l1,l2,l3;
        f2hilo(a.x,h0,l0); f2hilo(a.y,h1,l1); f2hilo(a.z,h2,l2); f2hilo(a.w,h3,l3);
        *(u16x4*)(Ahi + row*AK + kk) = (u16x4){h0,h1,h2,h3};
        *(u16x4*)(Alo + row*AK + kk) = (u16x4){l0,l1,l2,l3};
      }
      int nn = (tid & 31) * 4;
      int kb = tid >> 5;
      #pragma unroll
      for(int r = 0; r < 4; ++r){
        int krow = r * 8 + kb;
        float4 bv = *(const float4*)(Wsrc + (long)(k0 + krow) * ldb + c0 + nn);
        unsigned short hh, ll;
        f2hilo(bv.x,hh,ll); Bhi[(nn+0)*AK + krow] = hh; Blo[(nn+0)*AK + krow] = ll;
        f2hilo(bv.y,hh,ll); Bhi[(nn+1)*AK + krow] = hh; Blo[(nn+1)*AK + krow] = ll;
        f2hilo(bv.z,hh,ll); Bhi[(nn+2)*AK + krow] = hh; Blo[(nn+2)*AK + krow] = ll;
        f2hilo(bv.w,hh,ll); Bhi[(nn+3)*AK + krow] = hh; Blo[(nn+3)*AK + krow] = ll;
      }
    }
    __syncthreads();
    u16x8 ah[4], al[4];
    #pragma unroll
    for(int mi = 0; mi < 4; ++mi){
      int off = (wm + mi*16 + lr)*AK + lg*8;
      ah[mi] = *(const u16x8*)(Ahi + off);
      al[mi] = *(const u16x8*)(Alo + off);
    }
    #pragma unroll
    for(int ni = 0; ni < 4; ++ni){
      int off = (wn + ni*16 + lr)*AK + lg*8;
      u16x8 bh = *(const u16x8*)(Bhi + off);
      u16x8 bl = *(const u16x8*)(Blo + off);
      #pragma unroll
      for(int mi = 0; mi < 4; ++mi){
        acc[mi][ni] = mfma16(ah[mi], bh, acc[mi][ni]);
        acc[mi][ni] = mfma16(ah[mi], bl, acc[mi][ni]);
        acc[mi][ni] = mfma16(al[mi], bh, acc[mi][ni]);
      }
    }
  }
  #pragma unroll
  for(int mi = 0; mi < 4; ++mi)
  #pragma unroll
  for(int ni = 0; ni < 4; ++ni){
    int row = m0 + wm + mi*16 + lg*4;
    int col = n0 + wn + ni*16 + lr;
    #pragma unroll
    for(int r = 0; r < 4; ++r)
      Craw[(long)(row + r) * NQKV + col] = acc[mi][ni][r];
  }
}

// ---------------- postprocess Q: rmsnorm + rope + scale-fold -> hi/lo (B,H,Q,D) ----------
__global__ __launch_bounds__(256) void pp_q(
    const float* __restrict__ Craw, const float* __restrict__ cosb,
    const float* __restrict__ sinb, const float* __restrict__ qw,
    unsigned short* __restrict__ Qhi, unsigned short* __restrict__ Qlo){
  int rid = blockIdx.x * 4 + (threadIdx.x >> 6);
  int lane = threadIdx.x & 63;
  int b = rid >> 15;
  int rem = rid & 32767;
  int q = rem >> 5;
  int h = rem & 31;
  long rowoff = (long)(b * Q_ + q) * NQKV + h * 128;
  float x1 = Craw[rowoff + lane];
  float x2 = Craw[rowoff + 64 + lane];
  float ss = x1*x1 + x2*x2;
  for(int o = 32; o; o >>= 1) ss += __shfl_xor(ss, o);
  float norm = rsqrtf(ss * (1.0f/128.0f) + 1e-6f);
  float xn1 = x1 * norm * qw[lane];
  float xn2 = x2 * norm * qw[64 + lane];
  long co = (long)(b * Q_ + q) * 128;
  float c1 = cosb[co + lane],      s1 = sinb[co + lane];
  float c2 = cosb[co + 64 + lane], s2 = sinb[co + 64 + lane];
  float o1 = (xn1 * c1 - xn2 * s1) * SCALE;
  float o2 = (xn2 * c2 + xn1 * s2) * SCALE;
  long dst = ((long)(b * H_ + h) * Q_ + q) * 128;
  unsigned short hh, ll;
  f2hilo(o1, hh, ll); Qhi[dst + lane] = hh;      Qlo[dst + lane] = ll;
  f2hilo(o2, hh, ll); Qhi[dst + 64 + lane] = hh; Qlo[dst + 64 + lane] = ll;
}

// ---------------- postprocess K,V: k rmsnorm+rope -> cache at s=P+q; v convert ----------
__global__ __launch_bounds__(256) void pp_kv(
    const float* __restrict__ Craw, const float* __restrict__ cosb,
    const float* __restrict__ sinb, const float* __restrict__ kw,
    unsigned short* __restrict__ Khi, unsigned short* __restrict__ Klo,
    unsigned short* __restrict__ Vb){
  int rid = blockIdx.x * 4 + (threadIdx.x >> 6);
  int lane = threadIdx.x & 63;
  int b = rid >> 13;
  int rem = rid & 8191;
  int q = rem >> 3;
  int kv = rem & 7;
  long rowoff = (long)(b * Q_ + q) * NQKV;
  float x1 = Craw[rowoff + 4096 + kv*128 + lane];
  float x2 = Craw[rowoff + 4096 + kv*128 + 64 + lane];
  float ss = x1*x1 + x2*x2;
  for(int o = 32; o; o >>= 1) ss += __shfl_xor(ss, o);
  float norm = rsqrtf(ss * (1.0f/128.0f) + 1e-6f);
  float xn1 = x1 * norm * kw[lane];
  float xn2 = x2 * norm * kw[64 + lane];
  long co = (long)(b * Q_ + q) * 128;
  float c1 = cosb[co + lane],      s1 = sinb[co + lane];
  float c2 = cosb[co + 64 + lane], s2 = sinb[co + 64 + lane];
  float o1 = xn1 * c1 - xn2 * s1;
  float o2 = xn2 * c2 + xn1 * s2;
  long dst = ((long)(b * KV_ + kv) * S_ + P_ + q) * 128;
  unsigned short hh, ll;
  f2hilo(o1, hh, ll); Khi[dst + lane] = hh;      Klo[dst + lane] = ll;
  f2hilo(o2, hh, ll); Khi[dst + 64 + lane] = hh; Klo[dst + 64 + lane] = ll;
  float v1 = Craw[rowoff + 5120 + kv*128 + lane];
  float v2 = Craw[rowoff + 5120 + kv*128 + 64 + lane];
  Vb[dst + lane] = f2bf(v1);
  Vb[dst + 64 + lane] = f2bf(v2);
}

// ---------------- flash attention: 64 q-rows/block, 64-key tiles --------------------------
#define KP 136  // padded K-row stride in LDS
#define VP 72   // padded Vt/P row stride
__global__ __launch_bounds__(256) void attn(
    const unsigned short* __restrict__ Qhi, const unsigned short* __restrict__ Qlo,
    const unsigned short* __restrict__ Khi_g, const unsigned short* __restrict__ Klo_g,
    const unsigned short* __restrict__ Vb,
    unsigned short* __restrict__ Ohi, unsigned short* __restrict__ Olo){
  __shared__ __align__(16) unsigned short Ks_hi[64*KP], Ks_lo[64*KP];
  __shared__ __align__(16) unsigned short Vt[128*VP];
  __shared__ __align__(16) unsigned short Ps[4][16*VP];
  int tid = threadIdx.x;
  int b = blockIdx.z, h = blockIdx.y, q0 = blockIdx.x * 64;
  int kv = h >> 2;
  int wid = tid >> 6, lane = tid & 63, lr = lane & 15, lg = lane >> 4;
  int q0w = q0 + wid * 16;
  u16x8 qh[4], ql[4];
  long qbase = ((long)(b * H_ + h) * Q_ + q0w + lr) * 128;
  #pragma unroll
  for(int c = 0; c < 4; ++c){
    qh[c] = *(const u16x8*)(Qhi + qbase + c*32 + lg*8);
    ql[c] = *(const u16x8*)(Qlo + qbase + c*32 + lg*8);
  }
  f32x4 zero = {0.f,0.f,0.f,0.f};
  f32x4 o[8];
  #pragma unroll
  for(int i = 0; i < 8; ++i) o[i] = zero;
  float m[4], l[4];
  #pragma unroll
  for(int r = 0; r < 4; ++r){ m[r] = -3.0e38f; l[r] = 0.f; }
  long kbase0 = (long)(b * KV_ + kv) * S_ * 128;
  int ntiles = 49 + blockIdx.x;
  int sr = tid >> 2, coff = (tid & 3) * 32;

  for(int st = 0; st < ntiles; ++st){
    int s0 = st * 64;
    __syncthreads();
    {
      const unsigned short* gh = Khi_g + kbase0 + (long)(s0 + sr) * 128 + coff;
      const unsigned short* gl = Klo_g + kbase0 + (long)(s0 + sr) * 128 + coff;
      #pragma unroll
      for(int u = 0; u < 4; ++u){
        *(u16x8*)(Ks_hi + sr*KP + coff + u*8) = *(const u16x8*)(gh + u*8);
        *(u16x8*)(Ks_lo + sr*KP + coff + u*8) = *(const u16x8*)(gl + u*8);
      }
      const unsigned short* vsrc = Vb + kbase0 + (long)(s0 + sr) * 128 + coff;
      #pragma unroll
      for(int u = 0; u < 4; ++u){
        u16x8 v = *(const u16x8*)(vsrc + u*8);
        #pragma unroll
        for(int j = 0; j < 8; ++j) Vt[(coff + u*8 + j)*VP + sr] = v[j];
      }
    }
    __syncthreads();
    f32x4 pacc[4];
    #pragma unroll
    for(int ni = 0; ni < 4; ++ni){
      f32x4 a = zero;
      int koff = (ni*16 + lr)*KP + lg*8;
      #pragma unroll
      for(int c = 0; c < 4; ++c){
        u16x8 kh = *(const u16x8*)(Ks_hi + koff + c*32);
        u16x8 kl = *(const u16x8*)(Ks_lo + koff + c*32);
        a = mfma16(qh[c], kh, a);
        a = mfma16(qh[c], kl, a);
        a = mfma16(ql[c], kh, a);
      }
      pacc[ni] = a;
    }
    if(s0 + 63 > P_ + q0w){
      #pragma unroll
      for(int ni = 0; ni < 4; ++ni){
        int skey = s0 + ni*16 + lr;
        #pragma unroll
        for(int r = 0; r < 4; ++r){
          int qrow = q0w + lg*4 + r;
          if(skey > P_ + qrow) pacc[ni][r] = -1e30f;
        }
      }
    }
    float fac[4];
    #pragma unroll
    for(int r = 0; r < 4; ++r){
      float tm = fmaxf(fmaxf(pacc[0][r], pacc[1][r]), fmaxf(pacc[2][r], pacc[3][r]));
      #pragma unroll
      for(int ofs = 1; ofs < 16; ofs <<= 1) tm = fmaxf(tm, __shfl_xor(tm, ofs));
      float mn = fmaxf(m[r], tm);
      fac[r] = __expf(m[r] - mn);
      m[r] = mn;
    }
    float rsum[4] = {0.f, 0.f, 0.f, 0.f};
    #pragma unroll
    for(int ni = 0; ni < 4; ++ni)
      #pragma unroll
      for(int r = 0; r < 4; ++r){
        float p = __expf(pacc[ni][r] - m[r]);
        pacc[ni][r] = p;
        rsum[r] += p;
      }
    #pragma unroll
    for(int r = 0; r < 4; ++r){
      float t = rsum[r];
      #pragma unroll
      for(int ofs = 1; ofs < 16; ofs <<= 1) t += __shfl_xor(t, ofs);
      l[r] = l[r] * fac[r] + t;
    }
    #pragma unroll
    for(int i = 0; i < 8; ++i)
      #pragma unroll
      for(int r = 0; r < 4; ++r) o[i][r] *= fac[r];
    #pragma unroll
    for(int ni = 0; ni < 4; ++ni)
      #pragma unroll
      for(int r = 0; r < 4; ++r)
        Ps[wid][(lg*4 + r)*VP + ni*16 + lr] = f2bf(pacc[ni][r]);
    #pragma unroll
    for(int c2 = 0; c2 < 2; ++c2){
      u16x8 pa = *(const u16x8*)(&Ps[wid][lr*VP + c2*32 + lg*8]);
      #pragma unroll
      for(int ni = 0; ni < 8; ++ni){
        u16x8 vb = *(const u16x8*)(Vt + (ni*16 + lr)*VP + c2*32 + lg*8);
        o[ni] = mfma16(pa, vb, o[ni]);
      }
    }
  }
  #pragma unroll
  for(int r = 0; r < 4; ++r){
    float inv = 1.0f / l[r];
    int qrow = q0w + lg*4 + r;
    long obase = (long)(b * Q_ + qrow) * 4096 + h * 128;
    #pragma unroll
    for(int ni = 0; ni < 8; ++ni){
      float val = o[ni][r] * inv;
      unsigned short hh, ll; f2hilo(val, hh, ll);
      Ohi[obase + ni*16 + lr] = hh;
      Olo[obase + ni*16 + lr] = ll;
    }
  }
}

// ---------------- GEMM: output projection, A = attn hi/lo bf16, B = Wo fp32 -------------
__global__ __launch_bounds__(256) void gemm_o(
    const unsigned short* __restrict__ Ahi_g, const unsigned short* __restrict__ Alo_g,
    const float* __restrict__ Wo, float* __restrict__ Out){
  __shared__ __align__(16) unsigned short Ahi[128*AK], Alo[128*AK], Bhi[128*AK], Blo[128*AK];
  int tid = threadIdx.x;
  int m0 = blockIdx.y * 128, n0 = blockIdx.x * 128;
  int wid = tid >> 6, lane = tid & 63, lr = lane & 15, lg = lane >> 4;
  int wm = (wid >> 1) * 64, wn = (wid & 1) * 64;
  f32x4 zero = {0.f,0.f,0.f,0.f};
  f32x4 acc[4][4];
  for(int mi=0;mi<4;++mi) for(int ni=0;ni<4;++ni) acc[mi][ni] = zero;

  for(int kt = 0; kt < 128; ++kt){
    int k0 = kt * 32;
    __syncthreads();
    {
      int row2 = tid >> 2, koff = (tid & 3) * 8;
      #pragma unroll
      for(int r = 0; r < 2; ++r){
        int row = r * 64 + row2;
        long src = (long)(m0 + row) * 4096 + k0 + koff;
        *(u16x8*)(Ahi + row*AK + koff) = *(const u16x8*)(Ahi_g + src);
        *(u16x8*)(Alo + row*AK + koff) = *(const u16x8*)(Alo_g + src);
      }
      int nn = (tid & 31) * 4, kb = tid >> 5;
      #pragma unroll
      for(int r = 0; r < 4; ++r){
        int krow = r * 8 + kb;
        float4 bv = *(const float4*)(Wo + (long)(k0 + krow) * 4096 + n0 + nn);
        unsigned short hh, ll;
        f2hilo(bv.x,hh,ll); Bhi[(nn+0)*AK + krow] = hh; Blo[(nn+0)*AK + krow] = ll;
        f2hilo(bv.y,hh,ll); Bhi[(nn+1)*AK + krow] = hh; Blo[(nn+1)*AK + krow] = ll;
        f2hilo(bv.z,hh,ll); Bhi[(nn+2)*AK + krow] = hh; Blo[(nn+2)*AK + krow] = ll;
        f2hilo(bv.w,hh,ll); Bhi[(nn+3)*AK + krow] = hh; Blo[(nn+3)*AK + krow] = ll;
      }
    }
    __syncthreads();
    u16x8 ah[4], al[4];
    #pragma unroll
    for(int mi = 0; mi < 4; ++mi){
      int off = (wm + mi*16 + lr)*AK + lg*8;
      ah[mi] = *(const u16x8*)(Ahi + off);
      al[mi] = *(const u16x8*)(Alo + off);
    }
    #pragma unroll
    for(int ni = 0; ni < 4; ++ni){
      int off = (wn + ni*16 + lr)*AK + lg*8;
      u16x8 bh = *(const u16x8*)(Bhi + off);
      u16x8 bl = *(const u16x8*)(Blo + off);
      #pragma unroll
      for(int mi = 0; mi < 4; ++mi){
        acc[mi][ni] = mfma16(ah[mi], bh, acc[mi][ni]);
        acc[mi][ni] = mfma16(ah[mi], bl, acc[mi][ni]);
        acc[mi][ni] = mfma16(al[mi], bh, acc[mi][ni]);
      }
    }
  }
  #pragma unroll
  for(int mi = 0; mi < 4; ++mi)
  #pragma unroll
  for(int ni = 0; ni < 4; ++ni){
    int row = m0 + wm + mi*16 + lg*4;
    int col = n0 + wn + ni*16 + lr;
    #pragma unroll
    for(int r = 0; r < 4; ++r)
      Out[(long)(row + r) * 4096 + col] = acc[mi][ni][r];
  }
}

extern "C" void kernel_launch(void* const* d_in, const int* in_sizes, int n_in,
                              void* d_out, int out_size, void* d_ws, size_t ws_size,
                              hipStream_t stream){
  const float* hs   = (const float*)d_in[0];
  const float* cosb = (const float*)d_in[1];
  const float* sinb = (const float*)d_in[2];
  const float* kc   = (const float*)d_in[3];
  const float* vc   = (const float*)d_in[4];
  const float* Wq   = (const float*)d_in[5];
  const float* Wk   = (const float*)d_in[6];
  const float* Wv   = (const float*)d_in[7];
  const float* Wo   = (const float*)d_in[8];
  const float* qw   = (const float*)d_in[9];
  const float* kw   = (const float*)d_in[10];
  char* ws = (char*)d_ws;
  float* Craw          = (float*)ws;                        // 50.3 MB (M x 6144 fp32)
  unsigned short* Ohi  = (unsigned short*)ws;               // alias over dead Craw
  unsigned short* Olo  = (unsigned short*)(ws + 16777216);
  unsigned short* Qhi  = (unsigned short*)(ws + 50331648);
  unsigned short* Qlo  = (unsigned short*)(ws + 67108864);
  unsigned short* KhiB = (unsigned short*)(ws + 83886080);
  unsigned short* KloB = (unsigned short*)(ws + 100663296);
  unsigned short* Vb   = (unsigned short*)(ws + 117440512);
  float* Out = (float*)d_out;

  cache_convert<<<dim3(2048), dim3(256), 0, stream>>>(kc, vc, KhiB, KloB, Vb);
  gemm_qkv<<<dim3(48, 16), dim3(256), 0, stream>>>(hs, Wq, Wk, Wv, Craw);
  pp_q<<<dim3(16384), dim3(256), 0, stream>>>(Craw, cosb, sinb, qw, Qhi, Qlo);
  pp_kv<<<dim3(4096), dim3(256), 0, stream>>>(Craw, cosb, sinb, kw, KhiB, KloB, Vb);
  attn<<<dim3(16, 32, 2), dim3(256), 0, stream>>>(Qhi, Qlo, KhiB, KloB, Vb, Ohi, Olo);
  gemm_o<<<dim3(32, 16), dim3(256), 0, stream>>>(Ohi, Olo, Wo, Out);
}

// Round 2
// 1218.738 us; speedup vs baseline: 1.7681x; 1.7681x over previous
//
#include <hip/hip_runtime.h>
#include <hip/hip_bf16.h>

#define B_ 2
#define Q_ 1024
#define P_ 3072
#define HID_ 4096
#define H_ 32
#define KV_ 8
#define D_ 128
#define S_ 4096
#define NQKV 6144
#define SCALE 0.08838834764831845f

typedef __attribute__((ext_vector_type(4))) float f32x4;
typedef __attribute__((ext_vector_type(8))) unsigned short u16x8;
typedef __attribute__((ext_vector_type(4))) unsigned short u16x4;
typedef __attribute__((ext_vector_type(8))) __bf16 bf16x8;

__device__ __forceinline__ unsigned short f2bf(float f){
  unsigned u = __builtin_bit_cast(unsigned, f);
  unsigned r = (u + 0x7FFFu + ((u >> 16) & 1u)) >> 16;
  return (unsigned short)r;
}
__device__ __forceinline__ float bf2f(unsigned short h){
  unsigned u = ((unsigned)h) << 16;
  return __builtin_bit_cast(float, u);
}
__device__ __forceinline__ void f2hilo(float f, unsigned short& h, unsigned short& l){
  h = f2bf(f);
  l = f2bf(f - bf2f(h));
}
__device__ __forceinline__ f32x4 mfma16(u16x8 a, u16x8 b, f32x4 c){
  return __builtin_amdgcn_mfma_f32_16x16x32_bf16(
      __builtin_bit_cast(bf16x8, a), __builtin_bit_cast(bf16x8, b), c, 0, 0, 0);
}
typedef const __attribute__((address_space(1))) void* gp1_t;
typedef __attribute__((address_space(3))) void* lp3_t;
__device__ __forceinline__ void gl16(const unsigned short* g, unsigned short* l){
  __builtin_amdgcn_global_load_lds((gp1_t)g, (lp3_t)l, 16, 0, 0);
}

// ---------------- convert hidden states: fp32 -> hi/lo bf16 planes (no transpose) --------
__global__ __launch_bounds__(256) void convert_hs(
    const float* __restrict__ X, unsigned short* __restrict__ Hh,
    unsigned short* __restrict__ Hl, int total4){
  for(int i4 = blockIdx.x * 256 + threadIdx.x; i4 < total4; i4 += gridDim.x * 256){
    long i = (long)i4 * 4;
    float4 x = *(const float4*)(X + i);
    unsigned short h0,h1,h2,h3,l0,l1,l2,l3;
    f2hilo(x.x,h0,l0); f2hilo(x.y,h1,l1); f2hilo(x.z,h2,l2); f2hilo(x.w,h3,l3);
    *(u16x4*)(Hh + i) = (u16x4){h0,h1,h2,h3};
    *(u16x4*)(Hl + i) = (u16x4){l0,l1,l2,l3};
  }
}

// ---------------- convert weights: W[k][n] fp32 -> WT[n_off+n][k] hi/lo bf16 (transpose) --
__global__ __launch_bounds__(256) void convert_wt(
    const float* __restrict__ W, unsigned short* __restrict__ Th,
    unsigned short* __restrict__ Tl, int ldn, int n_off){
  __shared__ float tile[64][65];
  int k0 = blockIdx.y * 64, n0 = blockIdx.x * 64;
  int tid = threadIdx.x;
  int r = tid >> 4, c = (tid & 15) * 4;
  #pragma unroll
  for(int j = 0; j < 4; ++j){
    float4 v = *(const float4*)(W + (long)(k0 + r + j*16) * ldn + n0 + c);
    tile[r + j*16][c] = v.x; tile[r + j*16][c+1] = v.y;
    tile[r + j*16][c+2] = v.z; tile[r + j*16][c+3] = v.w;
  }
  __syncthreads();
  #pragma unroll
  for(int j = 0; j < 4; ++j){
    int n = r + j*16;
    unsigned short h[4], l[4];
    #pragma unroll
    for(int u = 0; u < 4; ++u) f2hilo(tile[c + u][n], h[u], l[u]);
    long o = (long)(n_off + n0 + n) * 4096 + k0 + c;
    *(u16x4*)(Th + o) = (u16x4){h[0],h[1],h[2],h[3]};
    *(u16x4*)(Tl + o) = (u16x4){l[0],l[1],l[2],l[3]};
  }
}

// ---------------- cache convert: fp32 (B,KV,P,D) -> hi/lo bf16 at s in [0,P) -------------
__global__ __launch_bounds__(256) void cache_convert(
    const float* __restrict__ kc, const float* __restrict__ vc,
    unsigned short* __restrict__ Khi, unsigned short* __restrict__ Klo,
    unsigned short* __restrict__ Vb){
  const int PD = P_ * D_;
  const long SD = (long)S_ * D_;
  int total4 = (B_ * KV_ * PD) >> 2;
  for(int i4 = blockIdx.x * 256 + threadIdx.x; i4 < total4; i4 += gridDim.x * 256){
    long i = (long)i4 * 4;
    int bkv = (int)(i / PD);
    int rem = (int)(i - (long)bkv * PD);
    long dst = (long)bkv * SD + rem;
    float4 k4 = *(const float4*)(kc + i);
    float4 v4 = *(const float4*)(vc + i);
    unsigned short h0,h1,h2,h3,l0,l1,l2,l3;
    f2hilo(k4.x,h0,l0); f2hilo(k4.y,h1,l1); f2hilo(k4.z,h2,l2); f2hilo(k4.w,h3,l3);
    *(u16x4*)(Khi + dst) = (u16x4){h0,h1,h2,h3};
    *(u16x4*)(Klo + dst) = (u16x4){l0,l1,l2,l3};
    *(u16x4*)(Vb  + dst) = (u16x4){f2bf(v4.x), f2bf(v4.y), f2bf(v4.z), f2bf(v4.w)};
  }
}

// ---------------- hi/lo bf16 GEMM: A[m][4096] planes x BT[n][4096] planes -> C fp32 ------
// 128x128 tile, BK=32, global_load_lds staging (linear LDS + pre-swizzled src),
// XOR-swizzled ds_read_b128, 48 MFMA/k-step/wave.
__global__ __launch_bounds__(256) void gemm_hilo(
    const unsigned short* __restrict__ Ahi, const unsigned short* __restrict__ Alo,
    const unsigned short* __restrict__ Bhi, const unsigned short* __restrict__ Blo,
    float* __restrict__ C, int nbx, int ldc){
  __shared__ __align__(16) unsigned short sAh[4096], sAl[4096], sBh[4096], sBl[4096];
  int tid = threadIdx.x;
  int nwg = nbx * 16;
  int lin = blockIdx.x;
  int cpx = nwg >> 3;
  int swz = (lin & 7) * cpx + (lin >> 3);   // XCD swizzle (nwg % 8 == 0)
  int bx = swz % nbx, by = swz / nbx;
  int m0 = by * 128, n0 = bx * 128;
  int lane = tid & 63, w = tid >> 6;
  int lr = lane & 15, lg = lane >> 4;
  int wm = (w >> 1) * 64, wn = (w & 1) * 64;
  // staging source addresses (inverse-swizzled so linear LDS image is swizzled)
  int rowi = w * 16 + (lane >> 2);
  int cchunk = ((lane & 3) ^ ((lane >> 3) & 3)) << 3;   // u16 units
  const unsigned short* aH = Ahi + (long)(m0 + rowi) * 4096 + cchunk;
  const unsigned short* aL = Alo + (long)(m0 + rowi) * 4096 + cchunk;
  const unsigned short* bH = Bhi + (long)(n0 + rowi) * 4096 + cchunk;
  const unsigned short* bL = Blo + (long)(n0 + rowi) * 4096 + cchunk;
  const int step2 = 64 * 4096;
  unsigned short* dAh = sAh + w * 512;
  unsigned short* dAl = sAl + w * 512;
  unsigned short* dBh = sBh + w * 512;
  unsigned short* dBl = sBl + w * 512;
  int rdcol = (lg * 8) ^ (((lr >> 1) & 3) << 3);        // swizzled read column (u16)
  f32x4 zero = {0.f,0.f,0.f,0.f};
  f32x4 acc[4][4];
  #pragma unroll
  for(int mi=0;mi<4;++mi)
    #pragma unroll
    for(int ni=0;ni<4;++ni) acc[mi][ni] = zero;

  for(int kt = 0; kt < 128; ++kt){
    int kk = kt * 32;
    __syncthreads();
    gl16(aH + kk, dAh);  gl16(aH + step2 + kk, dAh + 2048);
    gl16(aL + kk, dAl);  gl16(aL + step2 + kk, dAl + 2048);
    gl16(bH + kk, dBh);  gl16(bH + step2 + kk, dBh + 2048);
    gl16(bL + kk, dBl);  gl16(bL + step2 + kk, dBl + 2048);
    __syncthreads();
    u16x8 ah[4], al[4];
    #pragma unroll
    for(int mi = 0; mi < 4; ++mi){
      int off = (wm + mi*16 + lr) * 32 + rdcol;
      ah[mi] = *(const u16x8*)(sAh + off);
      al[mi] = *(const u16x8*)(sAl + off);
    }
    #pragma unroll
    for(int ni = 0; ni < 4; ++ni){
      int off = (wn + ni*16 + lr) * 32 + rdcol;
      u16x8 bh = *(const u16x8*)(sBh + off);
      u16x8 bl = *(const u16x8*)(sBl + off);
      #pragma unroll
      for(int mi = 0; mi < 4; ++mi){
        acc[mi][ni] = mfma16(ah[mi], bh, acc[mi][ni]);
        acc[mi][ni] = mfma16(ah[mi], bl, acc[mi][ni]);
        acc[mi][ni] = mfma16(al[mi], bh, acc[mi][ni]);
      }
    }
  }
  #pragma unroll
  for(int mi = 0; mi < 4; ++mi)
    #pragma unroll
    for(int r = 0; r < 4; ++r){
      long rowoff = (long)(m0 + wm + mi*16 + lg*4 + r) * ldc + n0 + wn + lr;
      #pragma unroll
      for(int ni = 0; ni < 4; ++ni)
        C[rowoff + ni*16] = acc[mi][ni][r];
    }
}

// ---------------- postprocess Q: rmsnorm + rope + scale-fold -> hi/lo (B,H,Q,D) ----------
__global__ __launch_bounds__(256) void pp_q(
    const float* __restrict__ Craw, const float* __restrict__ cosb,
    const float* __restrict__ sinb, const float* __restrict__ qw,
    unsigned short* __restrict__ Qhi, unsigned short* __restrict__ Qlo){
  int rid = blockIdx.x * 4 + (threadIdx.x >> 6);
  int lane = threadIdx.x & 63;
  int b = rid >> 15;
  int rem = rid & 32767;
  int q = rem >> 5;
  int h = rem & 31;
  long rowoff = (long)(b * Q_ + q) * NQKV + h * 128;
  float x1 = Craw[rowoff + lane];
  float x2 = Craw[rowoff + 64 + lane];
  float ss = x1*x1 + x2*x2;
  for(int o = 32; o; o >>= 1) ss += __shfl_xor(ss, o);
  float norm = rsqrtf(ss * (1.0f/128.0f) + 1e-6f);
  float xn1 = x1 * norm * qw[lane];
  float xn2 = x2 * norm * qw[64 + lane];
  long co = (long)(b * Q_ + q) * 128;
  float c1 = cosb[co + lane],      s1 = sinb[co + lane];
  float c2 = cosb[co + 64 + lane], s2 = sinb[co + 64 + lane];
  float o1 = (xn1 * c1 - xn2 * s1) * SCALE;
  float o2 = (xn2 * c2 + xn1 * s2) * SCALE;
  long dst = ((long)(b * H_ + h) * Q_ + q) * 128;
  unsigned short hh, ll;
  f2hilo(o1, hh, ll); Qhi[dst + lane] = hh;      Qlo[dst + lane] = ll;
  f2hilo(o2, hh, ll); Qhi[dst + 64 + lane] = hh; Qlo[dst + 64 + lane] = ll;
}

// ---------------- postprocess K,V: k rmsnorm+rope -> cache at s=P+q; v convert ----------
__global__ __launch_bounds__(256) void pp_kv(
    const float* __restrict__ Craw, const float* __restrict__ cosb,
    const float* __restrict__ sinb, const float* __restrict__ kw,
    unsigned short* __restrict__ Khi, unsigned short* __restrict__ Klo,
    unsigned short* __restrict__ Vb){
  int rid = blockIdx.x * 4 + (threadIdx.x >> 6);
  int lane = threadIdx.x & 63;
  int b = rid >> 13;
  int rem = rid & 8191;
  int q = rem >> 3;
  int kv = rem & 7;
  long rowoff = (long)(b * Q_ + q) * NQKV;
  float x1 = Craw[rowoff + 4096 + kv*128 + lane];
  float x2 = Craw[rowoff + 4096 + kv*128 + 64 + lane];
  float ss = x1*x1 + x2*x2;
  for(int o = 32; o; o >>= 1) ss += __shfl_xor(ss, o);
  float norm = rsqrtf(ss * (1.0f/128.0f) + 1e-6f);
  float xn1 = x1 * norm * kw[lane];
  float xn2 = x2 * norm * kw[64 + lane];
  long co = (long)(b * Q_ + q) * 128;
  float c1 = cosb[co + lane],      s1 = sinb[co + lane];
  float c2 = cosb[co + 64 + lane], s2 = sinb[co + 64 + lane];
  float o1 = xn1 * c1 - xn2 * s1;
  float o2 = xn2 * c2 + xn1 * s2;
  long dst = ((long)(b * KV_ + kv) * S_ + P_ + q) * 128;
  unsigned short hh, ll;
  f2hilo(o1, hh, ll); Khi[dst + lane] = hh;      Klo[dst + lane] = ll;
  f2hilo(o2, hh, ll); Khi[dst + 64 + lane] = hh; Klo[dst + 64 + lane] = ll;
  float v1 = Craw[rowoff + 5120 + kv*128 + lane];
  float v2 = Craw[rowoff + 5120 + kv*128 + 64 + lane];
  Vb[dst + lane] = f2bf(v1);
  Vb[dst + 64 + lane] = f2bf(v2);
}

// ---------------- flash attention: 64 q-rows/block, 64-key tiles --------------------------
#define KP 136
#define VP 72
__global__ __launch_bounds__(256) void attn(
    const unsigned short* __restrict__ Qhi, const unsigned short* __restrict__ Qlo,
    const unsigned short* __restrict__ Khi_g, const unsigned short* __restrict__ Klo_g,
    const unsigned short* __restrict__ Vb,
    unsigned short* __restrict__ Ohi, unsigned short* __restrict__ Olo){
  __shared__ __align__(16) unsigned short Ks_hi[64*KP], Ks_lo[64*KP];
  __shared__ __align__(16) unsigned short Vt[128*VP];
  __shared__ __align__(16) unsigned short Ps[4][16*VP];
  int tid = threadIdx.x;
  int b = blockIdx.z, h = blockIdx.y, q0 = blockIdx.x * 64;
  int kv = h >> 2;
  int wid = tid >> 6, lane = tid & 63, lr = lane & 15, lg = lane >> 4;
  int q0w = q0 + wid * 16;
  u16x8 qh[4], ql[4];
  long qbase = ((long)(b * H_ + h) * Q_ + q0w + lr) * 128;
  #pragma unroll
  for(int c = 0; c < 4; ++c){
    qh[c] = *(const u16x8*)(Qhi + qbase + c*32 + lg*8);
    ql[c] = *(const u16x8*)(Qlo + qbase + c*32 + lg*8);
  }
  f32x4 zero = {0.f,0.f,0.f,0.f};
  f32x4 o[8];
  #pragma unroll
  for(int i = 0; i < 8; ++i) o[i] = zero;
  float m[4], l[4];
  #pragma unroll
  for(int r = 0; r < 4; ++r){ m[r] = -3.0e38f; l[r] = 0.f; }
  long kbase0 = (long)(b * KV_ + kv) * S_ * 128;
  int ntiles = 49 + blockIdx.x;
  int sr = tid >> 2, coff = (tid & 3) * 32;

  for(int st = 0; st < ntiles; ++st){
    int s0 = st * 64;
    __syncthreads();
    {
      const unsigned short* gh = Khi_g + kbase0 + (long)(s0 + sr) * 128 + coff;
      const unsigned short* gl = Klo_g + kbase0 + (long)(s0 + sr) * 128 + coff;
      #pragma unroll
      for(int u = 0; u < 4; ++u){
        *(u16x8*)(Ks_hi + sr*KP + coff + u*8) = *(const u16x8*)(gh + u*8);
        *(u16x8*)(Ks_lo + sr*KP + coff + u*8) = *(const u16x8*)(gl + u*8);
      }
      const unsigned short* vsrc = Vb + kbase0 + (long)(s0 + sr) * 128 + coff;
      #pragma unroll
      for(int u = 0; u < 4; ++u){
        u16x8 v = *(const u16x8*)(vsrc + u*8);
        #pragma unroll
        for(int j = 0; j < 8; ++j) Vt[(coff + u*8 + j)*VP + sr] = v[j];
      }
    }
    __syncthreads();
    f32x4 pacc[4];
    #pragma unroll
    for(int ni = 0; ni < 4; ++ni){
      f32x4 a = zero;
      int koff = (ni*16 + lr)*KP + lg*8;
      #pragma unroll
      for(int c = 0; c < 4; ++c){
        u16x8 kh = *(const u16x8*)(Ks_hi + koff + c*32);
        u16x8 kl = *(const u16x8*)(Ks_lo + koff + c*32);
        a = mfma16(qh[c], kh, a);
        a = mfma16(qh[c], kl, a);
        a = mfma16(ql[c], kh, a);
      }
      pacc[ni] = a;
    }
    if(s0 + 63 > P_ + q0w){
      #pragma unroll
      for(int ni = 0; ni < 4; ++ni){
        int skey = s0 + ni*16 + lr;
        #pragma unroll
        for(int r = 0; r < 4; ++r){
          int qrow = q0w + lg*4 + r;
          if(skey > P_ + qrow) pacc[ni][r] = -1e30f;
        }
      }
    }
    float fac[4];
    #pragma unroll
    for(int r = 0; r < 4; ++r){
      float tm = fmaxf(fmaxf(pacc[0][r], pacc[1][r]), fmaxf(pacc[2][r], pacc[3][r]));
      #pragma unroll
      for(int ofs = 1; ofs < 16; ofs <<= 1) tm = fmaxf(tm, __shfl_xor(tm, ofs));
      float mn = fmaxf(m[r], tm);
      fac[r] = __expf(m[r] - mn);
      m[r] = mn;
    }
    float rsum[4] = {0.f, 0.f, 0.f, 0.f};
    #pragma unroll
    for(int ni = 0; ni < 4; ++ni)
      #pragma unroll
      for(int r = 0; r < 4; ++r){
        float p = __expf(pacc[ni][r] - m[r]);
        pacc[ni][r] = p;
        rsum[r] += p;
      }
    #pragma unroll
    for(int r = 0; r < 4; ++r){
      float t = rsum[r];
      #pragma unroll
      for(int ofs = 1; ofs < 16; ofs <<= 1) t += __shfl_xor(t, ofs);
      l[r] = l[r] * fac[r] + t;
    }
    #pragma unroll
    for(int i = 0; i < 8; ++i)
      #pragma unroll
      for(int r = 0; r < 4; ++r) o[i][r] *= fac[r];
    #pragma unroll
    for(int ni = 0; ni < 4; ++ni)
      #pragma unroll
      for(int r = 0; r < 4; ++r)
        Ps[wid][(lg*4 + r)*VP + ni*16 + lr] = f2bf(pacc[ni][r]);
    #pragma unroll
    for(int c2 = 0; c2 < 2; ++c2){
      u16x8 pa = *(const u16x8*)(&Ps[wid][lr*VP + c2*32 + lg*8]);
      #pragma unroll
      for(int ni = 0; ni < 8; ++ni){
        u16x8 vb = *(const u16x8*)(Vt + (ni*16 + lr)*VP + c2*32 + lg*8);
        o[ni] = mfma16(pa, vb, o[ni]);
      }
    }
  }
  #pragma unroll
  for(int r = 0; r < 4; ++r){
    float inv = 1.0f / l[r];
    int qrow = q0w + lg*4 + r;
    long obase = (long)(b * Q_ + qrow) * 4096 + h * 128;
    #pragma unroll
    for(int ni = 0; ni < 8; ++ni){
      float val = o[ni][r] * inv;
      unsigned short hh, ll; f2hilo(val, hh, ll);
      Ohi[obase + ni*16 + lr] = hh;
      Olo[obase + ni*16 + lr] = ll;
    }
  }
}

extern "C" void kernel_launch(void* const* d_in, const int* in_sizes, int n_in,
                              void* d_out, int out_size, void* d_ws, size_t ws_size,
                              hipStream_t stream){
  const float* hs   = (const float*)d_in[0];
  const float* cosb = (const float*)d_in[1];
  const float* sinb = (const float*)d_in[2];
  const float* kc   = (const float*)d_in[3];
  const float* vc   = (const float*)d_in[4];
  const float* Wq   = (const float*)d_in[5];
  const float* Wk   = (const float*)d_in[6];
  const float* Wv   = (const float*)d_in[7];
  const float* Wo   = (const float*)d_in[8];
  const float* qw   = (const float*)d_in[9];
  const float* kw   = (const float*)d_in[10];
  char* ws = (char*)d_ws;
  // layout (bytes):
  // [0, 50.3M)      Craw fp32 2048x6144   -> later Ohi@0 (16.8M) + Olo@16.8M
  // [50.3M, 151.0M) WT hi/lo 6144x4096    -> later WoT hi@50.3M lo@83.9M (4096x4096)
  // [151.0M, 184.5M) Ahs hi/lo 2048x4096  -> later Qhi@151.0M Qlo@167.8M
  // [184.5M, 234.9M) Khi / Klo / Vb caches (2,8,4096,128)
  float* Craw          = (float*)ws;
  unsigned short* OH   = (unsigned short*)ws;
  unsigned short* OL   = (unsigned short*)(ws + 16777216);
  unsigned short* WTh  = (unsigned short*)(ws + 50331648);
  unsigned short* WTl  = (unsigned short*)(ws + 100663296);
  unsigned short* WoTh = (unsigned short*)(ws + 50331648);
  unsigned short* WoTl = (unsigned short*)(ws + 83886080);
  unsigned short* AH   = (unsigned short*)(ws + 150994944);
  unsigned short* AL   = (unsigned short*)(ws + 167772160);
  unsigned short* QH   = (unsigned short*)(ws + 150994944);
  unsigned short* QL   = (unsigned short*)(ws + 167772160);
  unsigned short* KH   = (unsigned short*)(ws + 184549376);
  unsigned short* KL   = (unsigned short*)(ws + 201326592);
  unsigned short* VB   = (unsigned short*)(ws + 218103808);
  float* Out = (float*)d_out;

  convert_hs<<<dim3(2048), dim3(256), 0, stream>>>(hs, AH, AL, (B_*Q_*HID_)/4);
  convert_wt<<<dim3(64,64), dim3(256), 0, stream>>>(Wq, WTh, WTl, 4096, 0);
  convert_wt<<<dim3(16,64), dim3(256), 0, stream>>>(Wk, WTh, WTl, 1024, 4096);
  convert_wt<<<dim3(16,64), dim3(256), 0, stream>>>(Wv, WTh, WTl, 1024, 5120);
  cache_convert<<<dim3(2048), dim3(256), 0, stream>>>(kc, vc, KH, KL, VB);
  gemm_hilo<<<dim3(768), dim3(256), 0, stream>>>(AH, AL, WTh, WTl, Craw, 48, NQKV);
  pp_q<<<dim3(16384), dim3(256), 0, stream>>>(Craw, cosb, sinb, qw, QH, QL);
  pp_kv<<<dim3(4096), dim3(256), 0, stream>>>(Craw, cosb, sinb, kw, KH, KL, VB);
  convert_wt<<<dim3(64,64), dim3(256), 0, stream>>>(Wo, WoTh, WoTl, 4096, 0);
  attn<<<dim3(16, 32, 2), dim3(256), 0, stream>>>(QH, QL, KH, KL, VB, OH, OL);
  gemm_hilo<<<dim3(512), dim3(256), 0, stream>>>(OH, OL, WoTh, WoTl, Out, 32, 4096);
}

// Round 3
// 1070.428 us; speedup vs baseline: 2.0131x; 1.1386x over previous
//
#include <hip/hip_runtime.h>
#include <hip/hip_bf16.h>

#define B_ 2
#define Q_ 1024
#define P_ 3072
#define HID_ 4096
#define H_ 32
#define KV_ 8
#define D_ 128
#define S_ 4096
#define NQKV 6144
#define SCALE 0.08838834764831845f

typedef __attribute__((ext_vector_type(4))) float f32x4;
typedef __attribute__((ext_vector_type(8))) unsigned short u16x8;
typedef __attribute__((ext_vector_type(4))) unsigned short u16x4;
typedef __attribute__((ext_vector_type(8))) __bf16 bf16x8;

__device__ __forceinline__ unsigned short f2bf(float f){
  unsigned u = __builtin_bit_cast(unsigned, f);
  unsigned r = (u + 0x7FFFu + ((u >> 16) & 1u)) >> 16;
  return (unsigned short)r;
}
__device__ __forceinline__ float bf2f(unsigned short h){
  unsigned u = ((unsigned)h) << 16;
  return __builtin_bit_cast(float, u);
}
__device__ __forceinline__ void f2hilo(float f, unsigned short& h, unsigned short& l){
  h = f2bf(f);
  l = f2bf(f - bf2f(h));
}
__device__ __forceinline__ f32x4 mfma16(u16x8 a, u16x8 b, f32x4 c){
  return __builtin_amdgcn_mfma_f32_16x16x32_bf16(
      __builtin_bit_cast(bf16x8, a), __builtin_bit_cast(bf16x8, b), c, 0, 0, 0);
}
typedef const __attribute__((address_space(1))) void* gp1_t;
typedef __attribute__((address_space(3))) void* lp3_t;
__device__ __forceinline__ void gl16(const unsigned short* g, unsigned short* l){
  __builtin_amdgcn_global_load_lds((gp1_t)g, (lp3_t)l, 16, 0, 0);
}

// ---------------- convert hidden states: fp32 -> hi/lo bf16 planes -----------------------
__global__ __launch_bounds__(256) void convert_hs(
    const float* __restrict__ X, unsigned short* __restrict__ Hh,
    unsigned short* __restrict__ Hl, int total4){
  for(int i4 = blockIdx.x * 256 + threadIdx.x; i4 < total4; i4 += gridDim.x * 256){
    long i = (long)i4 * 4;
    float4 x = *(const float4*)(X + i);
    unsigned short h0,h1,h2,h3,l0,l1,l2,l3;
    f2hilo(x.x,h0,l0); f2hilo(x.y,h1,l1); f2hilo(x.z,h2,l2); f2hilo(x.w,h3,l3);
    *(u16x4*)(Hh + i) = (u16x4){h0,h1,h2,h3};
    *(u16x4*)(Hl + i) = (u16x4){l0,l1,l2,l3};
  }
}

// ---------------- convert weights: W[k][n] fp32 -> WT[n_off+n][k] hi/lo bf16 --------------
__global__ __launch_bounds__(256) void convert_wt(
    const float* __restrict__ W, unsigned short* __restrict__ Th,
    unsigned short* __restrict__ Tl, int ldn, int n_off){
  __shared__ float tile[64][65];
  int k0 = blockIdx.y * 64, n0 = blockIdx.x * 64;
  int tid = threadIdx.x;
  int r = tid >> 4, c = (tid & 15) * 4;
  #pragma unroll
  for(int j = 0; j < 4; ++j){
    float4 v = *(const float4*)(W + (long)(k0 + r + j*16) * ldn + n0 + c);
    tile[r + j*16][c] = v.x; tile[r + j*16][c+1] = v.y;
    tile[r + j*16][c+2] = v.z; tile[r + j*16][c+3] = v.w;
  }
  __syncthreads();
  #pragma unroll
  for(int j = 0; j < 4; ++j){
    int n = r + j*16;
    unsigned short h[4], l[4];
    #pragma unroll
    for(int u = 0; u < 4; ++u) f2hilo(tile[c + u][n], h[u], l[u]);
    long o = (long)(n_off + n0 + n) * 4096 + k0 + c;
    *(u16x4*)(Th + o) = (u16x4){h[0],h[1],h[2],h[3]};
    *(u16x4*)(Tl + o) = (u16x4){l[0],l[1],l[2],l[3]};
  }
}

// ---------------- cache K: fp32 (B,KV,P,D) -> single bf16 at s in [0,P) ------------------
__global__ __launch_bounds__(256) void cache_k(
    const float* __restrict__ kc, unsigned short* __restrict__ Kb){
  const int PD = P_ * D_;
  const long SD = (long)S_ * D_;
  int total4 = (B_ * KV_ * PD) >> 2;
  for(int i4 = blockIdx.x * 256 + threadIdx.x; i4 < total4; i4 += gridDim.x * 256){
    long i = (long)i4 * 4;
    int bkv = (int)(i / PD);
    int rem = (int)(i - (long)bkv * PD);
    long dst = (long)bkv * SD + rem;
    float4 k4 = *(const float4*)(kc + i);
    *(u16x4*)(Kb + dst) = (u16x4){f2bf(k4.x), f2bf(k4.y), f2bf(k4.z), f2bf(k4.w)};
  }
}

// ---------------- cache V transpose: fp32 (B,KV,P,D) -> VT bf16 [b,kv][d][s] -------------
__global__ __launch_bounds__(256) void cache_vt(
    const float* __restrict__ vc, unsigned short* __restrict__ VT){
  __shared__ unsigned short T[128][72];
  int bkv = blockIdx.y;
  int s0 = blockIdx.x * 64;
  int tid = threadIdx.x;
  int r = tid >> 2, dblk = (tid & 3) * 32;
  const float* src = vc + ((long)bkv * P_ + s0 + r) * 128 + dblk;
  #pragma unroll
  for(int u = 0; u < 8; ++u){
    float4 v = *(const float4*)(src + u*4);
    T[dblk + u*4 + 0][r] = f2bf(v.x);
    T[dblk + u*4 + 1][r] = f2bf(v.y);
    T[dblk + u*4 + 2][r] = f2bf(v.z);
    T[dblk + u*4 + 3][r] = f2bf(v.w);
  }
  __syncthreads();
  int d = tid >> 1, sh = (tid & 1) * 32;
  unsigned short* dst = VT + ((long)bkv * 128 + d) * S_ + s0 + sh;
  #pragma unroll
  for(int u = 0; u < 4; ++u){
    u16x8 v;
    #pragma unroll
    for(int j = 0; j < 8; ++j) v[j] = T[d][sh + u*8 + j];
    *(u16x8*)(dst + u*8) = v;
  }
}

// ---------------- hi/lo bf16 GEMM (unchanged structure) ----------------------------------
__global__ __launch_bounds__(256) void gemm_hilo(
    const unsigned short* __restrict__ Ahi, const unsigned short* __restrict__ Alo,
    const unsigned short* __restrict__ Bhi, const unsigned short* __restrict__ Blo,
    float* __restrict__ C, int nbx, int ldc){
  __shared__ __align__(16) unsigned short sAh[4096], sAl[4096], sBh[4096], sBl[4096];
  int tid = threadIdx.x;
  int nwg = nbx * 16;
  int lin = blockIdx.x;
  int cpx = nwg >> 3;
  int swz = (lin & 7) * cpx + (lin >> 3);
  int bx = swz % nbx, by = swz / nbx;
  int m0 = by * 128, n0 = bx * 128;
  int lane = tid & 63, w = tid >> 6;
  int lr = lane & 15, lg = lane >> 4;
  int wm = (w >> 1) * 64, wn = (w & 1) * 64;
  int rowi = w * 16 + (lane >> 2);
  int cchunk = ((lane & 3) ^ ((lane >> 3) & 3)) << 3;
  const unsigned short* aH = Ahi + (long)(m0 + rowi) * 4096 + cchunk;
  const unsigned short* aL = Alo + (long)(m0 + rowi) * 4096 + cchunk;
  const unsigned short* bH = Bhi + (long)(n0 + rowi) * 4096 + cchunk;
  const unsigned short* bL = Blo + (long)(n0 + rowi) * 4096 + cchunk;
  const int step2 = 64 * 4096;
  unsigned short* dAh = sAh + w * 512;
  unsigned short* dAl = sAl + w * 512;
  unsigned short* dBh = sBh + w * 512;
  unsigned short* dBl = sBl + w * 512;
  int rdcol = (lg * 8) ^ (((lr >> 1) & 3) << 3);
  f32x4 zero = {0.f,0.f,0.f,0.f};
  f32x4 acc[4][4];
  #pragma unroll
  for(int mi=0;mi<4;++mi)
    #pragma unroll
    for(int ni=0;ni<4;++ni) acc[mi][ni] = zero;

  for(int kt = 0; kt < 128; ++kt){
    int kk = kt * 32;
    __syncthreads();
    gl16(aH + kk, dAh);  gl16(aH + step2 + kk, dAh + 2048);
    gl16(aL + kk, dAl);  gl16(aL + step2 + kk, dAl + 2048);
    gl16(bH + kk, dBh);  gl16(bH + step2 + kk, dBh + 2048);
    gl16(bL + kk, dBl);  gl16(bL + step2 + kk, dBl + 2048);
    __syncthreads();
    u16x8 ah[4], al[4];
    #pragma unroll
    for(int mi = 0; mi < 4; ++mi){
      int off = (wm + mi*16 + lr) * 32 + rdcol;
      ah[mi] = *(const u16x8*)(sAh + off);
      al[mi] = *(const u16x8*)(sAl + off);
    }
    #pragma unroll
    for(int ni = 0; ni < 4; ++ni){
      int off = (wn + ni*16 + lr) * 32 + rdcol;
      u16x8 bh = *(const u16x8*)(sBh + off);
      u16x8 bl = *(const u16x8*)(sBl + off);
      #pragma unroll
      for(int mi = 0; mi < 4; ++mi){
        acc[mi][ni] = mfma16(ah[mi], bh, acc[mi][ni]);
        acc[mi][ni] = mfma16(ah[mi], bl, acc[mi][ni]);
        acc[mi][ni] = mfma16(al[mi], bh, acc[mi][ni]);
      }
    }
  }
  #pragma unroll
  for(int mi = 0; mi < 4; ++mi)
    #pragma unroll
    for(int r = 0; r < 4; ++r){
      long rowoff = (long)(m0 + wm + mi*16 + lg*4 + r) * ldc + n0 + wn + lr;
      #pragma unroll
      for(int ni = 0; ni < 4; ++ni)
        C[rowoff + ni*16] = acc[mi][ni][r];
    }
}

// ---------------- postprocess Q: rmsnorm + rope + scale -> single bf16 (B,H,Q,D) ---------
__global__ __launch_bounds__(256) void pp_q(
    const float* __restrict__ Craw, const float* __restrict__ cosb,
    const float* __restrict__ sinb, const float* __restrict__ qw,
    unsigned short* __restrict__ Qb){
  int rid = blockIdx.x * 4 + (threadIdx.x >> 6);
  int lane = threadIdx.x & 63;
  int b = rid >> 15;
  int rem = rid & 32767;
  int q = rem >> 5;
  int h = rem & 31;
  long rowoff = (long)(b * Q_ + q) * NQKV + h * 128;
  float x1 = Craw[rowoff + lane];
  float x2 = Craw[rowoff + 64 + lane];
  float ss = x1*x1 + x2*x2;
  for(int o = 32; o; o >>= 1) ss += __shfl_xor(ss, o);
  float norm = rsqrtf(ss * (1.0f/128.0f) + 1e-6f);
  float xn1 = x1 * norm * qw[lane];
  float xn2 = x2 * norm * qw[64 + lane];
  long co = (long)(b * Q_ + q) * 128;
  float c1 = cosb[co + lane],      s1 = sinb[co + lane];
  float c2 = cosb[co + 64 + lane], s2 = sinb[co + 64 + lane];
  float o1 = (xn1 * c1 - xn2 * s1) * SCALE;
  float o2 = (xn2 * c2 + xn1 * s2) * SCALE;
  long dst = ((long)(b * H_ + h) * Q_ + q) * 128;
  Qb[dst + lane] = f2bf(o1);
  Qb[dst + 64 + lane] = f2bf(o2);
}

// ---------------- postprocess K,V: k rmsnorm+rope single bf16; v -> VT scatter -----------
__global__ __launch_bounds__(256) void pp_kv(
    const float* __restrict__ Craw, const float* __restrict__ cosb,
    const float* __restrict__ sinb, const float* __restrict__ kw,
    unsigned short* __restrict__ Kb, unsigned short* __restrict__ VT){
  int rid = blockIdx.x * 4 + (threadIdx.x >> 6);
  int lane = threadIdx.x & 63;
  int b = rid >> 13;
  int rem = rid & 8191;
  int q = rem >> 3;
  int kv = rem & 7;
  int bkv = b * KV_ + kv;
  long rowoff = (long)(b * Q_ + q) * NQKV;
  float x1 = Craw[rowoff + 4096 + kv*128 + lane];
  float x2 = Craw[rowoff + 4096 + kv*128 + 64 + lane];
  float ss = x1*x1 + x2*x2;
  for(int o = 32; o; o >>= 1) ss += __shfl_xor(ss, o);
  float norm = rsqrtf(ss * (1.0f/128.0f) + 1e-6f);
  float xn1 = x1 * norm * kw[lane];
  float xn2 = x2 * norm * kw[64 + lane];
  long co = (long)(b * Q_ + q) * 128;
  float c1 = cosb[co + lane],      s1 = sinb[co + lane];
  float c2 = cosb[co + 64 + lane], s2 = sinb[co + 64 + lane];
  long dst = ((long)bkv * S_ + P_ + q) * 128;
  Kb[dst + lane]      = f2bf(xn1 * c1 - xn2 * s1);
  Kb[dst + 64 + lane] = f2bf(xn2 * c2 + xn1 * s2);
  float v1 = Craw[rowoff + 5120 + kv*128 + lane];
  float v2 = Craw[rowoff + 5120 + kv*128 + 64 + lane];
  VT[((long)bkv * 128 + lane) * S_ + P_ + q]      = f2bf(v1);
  VT[((long)bkv * 128 + 64 + lane) * S_ + P_ + q] = f2bf(v2);
}

// ---------------- flash attention: 128 q/block, 32 q/wave, 64-key tiles ------------------
#define PSL 72
__global__ __launch_bounds__(256) void attn(
    const unsigned short* __restrict__ Qg, const unsigned short* __restrict__ Kg,
    const unsigned short* __restrict__ VTg,
    unsigned short* __restrict__ Ohi, unsigned short* __restrict__ Olo){
  __shared__ __align__(16) unsigned short Ks[64*128];
  __shared__ __align__(16) unsigned short Vs[128*64];
  __shared__ __align__(16) unsigned short Ps[4][32*PSL];
  int tid = threadIdx.x;
  int b = blockIdx.z, h = blockIdx.y, q0 = blockIdx.x * 128;
  int kvh = h >> 2;
  int w = tid >> 6, lane = tid & 63, lr = lane & 15, lg = lane >> 4;
  int q0w = q0 + w * 32;
  u16x8 qh[2][4];
  #pragma unroll
  for(int mi = 0; mi < 2; ++mi){
    long qbase = ((long)(b * H_ + h) * Q_ + q0w + mi*16 + lr) * 128;
    #pragma unroll
    for(int c = 0; c < 4; ++c)
      qh[mi][c] = *(const u16x8*)(Qg + qbase + c*32 + lg*8);
  }
  f32x4 zero = {0.f,0.f,0.f,0.f};
  f32x4 o[2][8];
  #pragma unroll
  for(int mi = 0; mi < 2; ++mi)
    #pragma unroll
    for(int i = 0; i < 8; ++i) o[mi][i] = zero;
  float m[2][4], l[2][4];
  #pragma unroll
  for(int mi = 0; mi < 2; ++mi)
    #pragma unroll
    for(int r = 0; r < 4; ++r){ m[mi][r] = -3.0e38f; l[mi][r] = 0.f; }
  long kb = (long)(b * KV_ + kvh) * S_ * 128;
  long vbase = (long)(b * KV_ + kvh) * 128 * (long)S_;
  int ntiles = 50 + 2 * blockIdx.x;
  int krsub = lane >> 4, kslot = lane & 15;
  int vrsub = lane >> 3, vcb = (lane & 7) ^ (lane >> 3);
  int lr7 = lr & 7;

  for(int st = 0; st < ntiles; ++st){
    int s0 = st * 64;
    __syncthreads();
    #pragma unroll
    for(int i = 0; i < 4; ++i){
      int r = w*16 + i*4 + krsub;
      int cb = kslot ^ ((i*4 + krsub) & 7);
      gl16(Kg + kb + (long)(s0 + r)*128 + cb*8, Ks + (w*16 + i*4)*128);
    }
    #pragma unroll
    for(int j = 0; j < 4; ++j){
      int d = w*32 + j*8 + vrsub;
      gl16(VTg + vbase + (long)d*S_ + s0 + vcb*8, Vs + (w*32 + j*8)*64);
    }
    __syncthreads();
    if(s0 <= P_ + q0w + 31){
      f32x4 pacc[2][4];
      #pragma unroll
      for(int mi = 0; mi < 2; ++mi)
        #pragma unroll
        for(int ni = 0; ni < 4; ++ni) pacc[mi][ni] = zero;
      #pragma unroll
      for(int ni = 0; ni < 4; ++ni)
        #pragma unroll
        for(int c = 0; c < 4; ++c){
          u16x8 kh = *(const u16x8*)(Ks + (ni*16 + lr)*128 + (((c*4 + lg) ^ lr7) << 3));
          pacc[0][ni] = mfma16(qh[0][c], kh, pacc[0][ni]);
          pacc[1][ni] = mfma16(qh[1][c], kh, pacc[1][ni]);
        }
      if(s0 + 63 > P_ + q0w){
        #pragma unroll
        for(int mi = 0; mi < 2; ++mi)
          #pragma unroll
          for(int ni = 0; ni < 4; ++ni){
            int skey = s0 + ni*16 + lr;
            #pragma unroll
            for(int r = 0; r < 4; ++r){
              int qrow = q0w + mi*16 + lg*4 + r;
              if(skey > P_ + qrow) pacc[mi][ni][r] = -1e30f;
            }
          }
      }
      float tmx[2][4];
      #pragma unroll
      for(int mi = 0; mi < 2; ++mi)
        #pragma unroll
        for(int r = 0; r < 4; ++r){
          float t = fmaxf(fmaxf(pacc[mi][0][r], pacc[mi][1][r]),
                          fmaxf(pacc[mi][2][r], pacc[mi][3][r]));
          #pragma unroll
          for(int ofs = 1; ofs < 16; ofs <<= 1) t = fmaxf(t, __shfl_xor(t, ofs));
          tmx[mi][r] = t;
        }
      int need = 0;
      #pragma unroll
      for(int mi = 0; mi < 2; ++mi)
        #pragma unroll
        for(int r = 0; r < 4; ++r) need |= (tmx[mi][r] > m[mi][r] + 8.f);
      if(__any(need)){
        #pragma unroll
        for(int mi = 0; mi < 2; ++mi)
          #pragma unroll
          for(int r = 0; r < 4; ++r){
            float mn = fmaxf(m[mi][r], tmx[mi][r]);
            float fac = __expf(m[mi][r] - mn);
            m[mi][r] = mn;
            l[mi][r] *= fac;
            #pragma unroll
            for(int ni = 0; ni < 8; ++ni) o[mi][ni][r] *= fac;
          }
      }
      float rsum[2][4] = {{0.f,0.f,0.f,0.f},{0.f,0.f,0.f,0.f}};
      #pragma unroll
      for(int mi = 0; mi < 2; ++mi)
        #pragma unroll
        for(int ni = 0; ni < 4; ++ni)
          #pragma unroll
          for(int r = 0; r < 4; ++r){
            float p = __expf(pacc[mi][ni][r] - m[mi][r]);
            pacc[mi][ni][r] = p;
            rsum[mi][r] += p;
          }
      #pragma unroll
      for(int mi = 0; mi < 2; ++mi)
        #pragma unroll
        for(int r = 0; r < 4; ++r){
          float t = rsum[mi][r];
          #pragma unroll
          for(int ofs = 1; ofs < 16; ofs <<= 1) t += __shfl_xor(t, ofs);
          l[mi][r] += t;
        }
      #pragma unroll
      for(int mi = 0; mi < 2; ++mi)
        #pragma unroll
        for(int ni = 0; ni < 4; ++ni)
          #pragma unroll
          for(int r = 0; r < 4; ++r)
            Ps[w][(mi*16 + lg*4 + r)*PSL + ni*16 + lr] = f2bf(pacc[mi][ni][r]);
      #pragma unroll
      for(int c2 = 0; c2 < 2; ++c2){
        u16x8 pa0 = *(const u16x8*)(&Ps[w][lr*PSL + c2*32 + lg*8]);
        u16x8 pa1 = *(const u16x8*)(&Ps[w][(16 + lr)*PSL + c2*32 + lg*8]);
        #pragma unroll
        for(int ni = 0; ni < 8; ++ni){
          u16x8 vbf = *(const u16x8*)(Vs + (ni*16 + lr)*64 + (((c2*4 + lg) ^ lr7) << 3));
          o[0][ni] = mfma16(pa0, vbf, o[0][ni]);
          o[1][ni] = mfma16(pa1, vbf, o[1][ni]);
        }
      }
    }
  }
  #pragma unroll
  for(int mi = 0; mi < 2; ++mi)
    #pragma unroll
    for(int r = 0; r < 4; ++r){
      float inv = 1.0f / l[mi][r];
      int qrow = q0w + mi*16 + lg*4 + r;
      long obase = (long)(b * Q_ + qrow) * 4096 + h * 128;
      #pragma unroll
      for(int ni = 0; ni < 8; ++ni){
        float val = o[mi][ni][r] * inv;
        unsigned short hh, ll; f2hilo(val, hh, ll);
        Ohi[obase + ni*16 + lr] = hh;
        Olo[obase + ni*16 + lr] = ll;
      }
    }
}

extern "C" void kernel_launch(void* const* d_in, const int* in_sizes, int n_in,
                              void* d_out, int out_size, void* d_ws, size_t ws_size,
                              hipStream_t stream){
  const float* hs   = (const float*)d_in[0];
  const float* cosb = (const float*)d_in[1];
  const float* sinb = (const float*)d_in[2];
  const float* kc   = (const float*)d_in[3];
  const float* vc   = (const float*)d_in[4];
  const float* Wq   = (const float*)d_in[5];
  const float* Wk   = (const float*)d_in[6];
  const float* Wv   = (const float*)d_in[7];
  const float* Wo   = (const float*)d_in[8];
  const float* qw   = (const float*)d_in[9];
  const float* kw   = (const float*)d_in[10];
  char* ws = (char*)d_ws;
  float* Craw          = (float*)ws;                        // 50.3 MB, dead after pp_*
  unsigned short* OH   = (unsigned short*)ws;               // alias over dead Craw
  unsigned short* OL   = (unsigned short*)(ws + 16777216);
  unsigned short* WTh  = (unsigned short*)(ws + 50331648);
  unsigned short* WTl  = (unsigned short*)(ws + 100663296);
  unsigned short* WoTh = (unsigned short*)(ws + 50331648);  // over dead WT
  unsigned short* WoTl = (unsigned short*)(ws + 83886080);
  unsigned short* AH   = (unsigned short*)(ws + 150994944);
  unsigned short* AL   = (unsigned short*)(ws + 167772160);
  unsigned short* QB   = (unsigned short*)(ws + 150994944); // over dead AH
  unsigned short* KB   = (unsigned short*)(ws + 184549376);
  unsigned short* VT   = (unsigned short*)(ws + 218103808);
  float* Out = (float*)d_out;

  convert_hs<<<dim3(2048), dim3(256), 0, stream>>>(hs, AH, AL, (B_*Q_*HID_)/4);
  convert_wt<<<dim3(64,64), dim3(256), 0, stream>>>(Wq, WTh, WTl, 4096, 0);
  convert_wt<<<dim3(16,64), dim3(256), 0, stream>>>(Wk, WTh, WTl, 1024, 4096);
  convert_wt<<<dim3(16,64), dim3(256), 0, stream>>>(Wv, WTh, WTl, 1024, 5120);
  cache_k<<<dim3(2048), dim3(256), 0, stream>>>(kc, KB);
  cache_vt<<<dim3(48, 16), dim3(256), 0, stream>>>(vc, VT);
  gemm_hilo<<<dim3(768), dim3(256), 0, stream>>>(AH, AL, WTh, WTl, Craw, 48, NQKV);
  pp_q<<<dim3(16384), dim3(256), 0, stream>>>(Craw, cosb, sinb, qw, QB);
  pp_kv<<<dim3(4096), dim3(256), 0, stream>>>(Craw, cosb, sinb, kw, KB, VT);
  convert_wt<<<dim3(64,64), dim3(256), 0, stream>>>(Wo, WoTh, WoTl, 4096, 0);
  attn<<<dim3(8, 32, 2), dim3(256), 0, stream>>>(QB, KB, VT, OH, OL);
  gemm_hilo<<<dim3(512), dim3(256), 0, stream>>>(OH, OL, WoTh, WoTl, Out, 32, 4096);
}

// Round 4
// 948.145 us; speedup vs baseline: 2.2728x; 1.1290x over previous
//
#include <hip/hip_runtime.h>
#include <hip/hip_bf16.h>

#define B_ 2
#define Q_ 1024
#define P_ 3072
#define HID_ 4096
#define H_ 32
#define KV_ 8
#define D_ 128
#define S_ 4096
#define NQKV 6144
// 1/sqrt(128) * log2(e)  (softmax runs in log2 domain)
#define QSCALE 0.1275174432f

typedef __attribute__((ext_vector_type(4))) float f32x4;
typedef __attribute__((ext_vector_type(8))) unsigned short u16x8;
typedef __attribute__((ext_vector_type(4))) unsigned short u16x4;
typedef __attribute__((ext_vector_type(8))) __bf16 bf16x8;

__device__ __forceinline__ unsigned short f2bf(float f){
  unsigned u = __builtin_bit_cast(unsigned, f);
  unsigned r = (u + 0x7FFFu + ((u >> 16) & 1u)) >> 16;
  return (unsigned short)r;
}
__device__ __forceinline__ float bf2f(unsigned short h){
  unsigned u = ((unsigned)h) << 16;
  return __builtin_bit_cast(float, u);
}
__device__ __forceinline__ void f2hilo(float f, unsigned short& h, unsigned short& l){
  h = f2bf(f);
  l = f2bf(f - bf2f(h));
}
__device__ __forceinline__ unsigned pk2bf(float lo, float hi){
  unsigned r;
  asm("v_cvt_pk_bf16_f32 %0, %1, %2" : "=v"(r) : "v"(lo), "v"(hi));
  return r;
}
__device__ __forceinline__ f32x4 mfma16(u16x8 a, u16x8 b, f32x4 c){
  return __builtin_amdgcn_mfma_f32_16x16x32_bf16(
      __builtin_bit_cast(bf16x8, a), __builtin_bit_cast(bf16x8, b), c, 0, 0, 0);
}
typedef const __attribute__((address_space(1))) void* gp1_t;
typedef __attribute__((address_space(3))) void* lp3_t;
__device__ __forceinline__ void gl16(const unsigned short* g, unsigned short* l){
  __builtin_amdgcn_global_load_lds((gp1_t)g, (lp3_t)l, 16, 0, 0);
}

// ---------------- convert hidden states: fp32 -> hi/lo bf16 planes -----------------------
__global__ __launch_bounds__(256) void convert_hs(
    const float* __restrict__ X, unsigned short* __restrict__ Hh,
    unsigned short* __restrict__ Hl, int total4){
  for(int i4 = blockIdx.x * 256 + threadIdx.x; i4 < total4; i4 += gridDim.x * 256){
    long i = (long)i4 * 4;
    float4 x = *(const float4*)(X + i);
    unsigned short h0,h1,h2,h3,l0,l1,l2,l3;
    f2hilo(x.x,h0,l0); f2hilo(x.y,h1,l1); f2hilo(x.z,h2,l2); f2hilo(x.w,h3,l3);
    *(u16x4*)(Hh + i) = (u16x4){h0,h1,h2,h3};
    *(u16x4*)(Hl + i) = (u16x4){l0,l1,l2,l3};
  }
}

// ---------------- convert weights: W[k][n] fp32 -> WT[n_off+n][k] hi/lo bf16 --------------
__global__ __launch_bounds__(256) void convert_wt(
    const float* __restrict__ W, unsigned short* __restrict__ Th,
    unsigned short* __restrict__ Tl, int ldn, int n_off){
  __shared__ float tile[64][65];
  int k0 = blockIdx.y * 64, n0 = blockIdx.x * 64;
  int tid = threadIdx.x;
  int r = tid >> 4, c = (tid & 15) * 4;
  #pragma unroll
  for(int j = 0; j < 4; ++j){
    float4 v = *(const float4*)(W + (long)(k0 + r + j*16) * ldn + n0 + c);
    tile[r + j*16][c] = v.x; tile[r + j*16][c+1] = v.y;
    tile[r + j*16][c+2] = v.z; tile[r + j*16][c+3] = v.w;
  }
  __syncthreads();
  #pragma unroll
  for(int j = 0; j < 4; ++j){
    int n = r + j*16;
    unsigned short h[4], l[4];
    #pragma unroll
    for(int u = 0; u < 4; ++u) f2hilo(tile[c + u][n], h[u], l[u]);
    long o = (long)(n_off + n0 + n) * 4096 + k0 + c;
    *(u16x4*)(Th + o) = (u16x4){h[0],h[1],h[2],h[3]};
    *(u16x4*)(Tl + o) = (u16x4){l[0],l[1],l[2],l[3]};
  }
}

// ---------------- cache K: fp32 (B,KV,P,D) -> single bf16 at s in [0,P) ------------------
__global__ __launch_bounds__(256) void cache_k(
    const float* __restrict__ kc, unsigned short* __restrict__ Kb){
  const int PD = P_ * D_;
  const long SD = (long)S_ * D_;
  int total4 = (B_ * KV_ * PD) >> 2;
  for(int i4 = blockIdx.x * 256 + threadIdx.x; i4 < total4; i4 += gridDim.x * 256){
    long i = (long)i4 * 4;
    int bkv = (int)(i / PD);
    int rem = (int)(i - (long)bkv * PD);
    long dst = (long)bkv * SD + rem;
    float4 k4 = *(const float4*)(kc + i);
    *(u16x4*)(Kb + dst) = (u16x4){f2bf(k4.x), f2bf(k4.y), f2bf(k4.z), f2bf(k4.w)};
  }
}

// ---------------- cache V transpose: fp32 (B,KV,P,D) -> VT bf16 [b,kv][d][s] -------------
__global__ __launch_bounds__(256) void cache_vt(
    const float* __restrict__ vc, unsigned short* __restrict__ VT){
  __shared__ unsigned short T[128][72];
  int bkv = blockIdx.y;
  int s0 = blockIdx.x * 64;
  int tid = threadIdx.x;
  int r = tid >> 2, dblk = (tid & 3) * 32;
  const float* src = vc + ((long)bkv * P_ + s0 + r) * 128 + dblk;
  #pragma unroll
  for(int u = 0; u < 8; ++u){
    float4 v = *(const float4*)(src + u*4);
    T[dblk + u*4 + 0][r] = f2bf(v.x);
    T[dblk + u*4 + 1][r] = f2bf(v.y);
    T[dblk + u*4 + 2][r] = f2bf(v.z);
    T[dblk + u*4 + 3][r] = f2bf(v.w);
  }
  __syncthreads();
  int d = tid >> 1, sh = (tid & 1) * 32;
  unsigned short* dst = VT + ((long)bkv * 128 + d) * S_ + s0 + sh;
  #pragma unroll
  for(int u = 0; u < 4; ++u){
    u16x8 v;
    #pragma unroll
    for(int j = 0; j < 8; ++j) v[j] = T[d][sh + u*8 + j];
    *(u16x8*)(dst + u*8) = v;
  }
}

// ---------------- hi/lo bf16 GEMM (unchanged) --------------------------------------------
__global__ __launch_bounds__(256) void gemm_hilo(
    const unsigned short* __restrict__ Ahi, const unsigned short* __restrict__ Alo,
    const unsigned short* __restrict__ Bhi, const unsigned short* __restrict__ Blo,
    float* __restrict__ C, int nbx, int ldc){
  __shared__ __align__(16) unsigned short sAh[4096], sAl[4096], sBh[4096], sBl[4096];
  int tid = threadIdx.x;
  int nwg = nbx * 16;
  int lin = blockIdx.x;
  int cpx = nwg >> 3;
  int swz = (lin & 7) * cpx + (lin >> 3);
  int bx = swz % nbx, by = swz / nbx;
  int m0 = by * 128, n0 = bx * 128;
  int lane = tid & 63, w = tid >> 6;
  int lr = lane & 15, lg = lane >> 4;
  int wm = (w >> 1) * 64, wn = (w & 1) * 64;
  int rowi = w * 16 + (lane >> 2);
  int cchunk = ((lane & 3) ^ ((lane >> 3) & 3)) << 3;
  const unsigned short* aH = Ahi + (long)(m0 + rowi) * 4096 + cchunk;
  const unsigned short* aL = Alo + (long)(m0 + rowi) * 4096 + cchunk;
  const unsigned short* bH = Bhi + (long)(n0 + rowi) * 4096 + cchunk;
  const unsigned short* bL = Blo + (long)(n0 + rowi) * 4096 + cchunk;
  const int step2 = 64 * 4096;
  unsigned short* dAh = sAh + w * 512;
  unsigned short* dAl = sAl + w * 512;
  unsigned short* dBh = sBh + w * 512;
  unsigned short* dBl = sBl + w * 512;
  int rdcol = (lg * 8) ^ (((lr >> 1) & 3) << 3);
  f32x4 zero = {0.f,0.f,0.f,0.f};
  f32x4 acc[4][4];
  #pragma unroll
  for(int mi=0;mi<4;++mi)
    #pragma unroll
    for(int ni=0;ni<4;++ni) acc[mi][ni] = zero;

  for(int kt = 0; kt < 128; ++kt){
    int kk = kt * 32;
    __syncthreads();
    gl16(aH + kk, dAh);  gl16(aH + step2 + kk, dAh + 2048);
    gl16(aL + kk, dAl);  gl16(aL + step2 + kk, dAl + 2048);
    gl16(bH + kk, dBh);  gl16(bH + step2 + kk, dBh + 2048);
    gl16(bL + kk, dBl);  gl16(bL + step2 + kk, dBl + 2048);
    __syncthreads();
    u16x8 ah[4], al[4];
    #pragma unroll
    for(int mi = 0; mi < 4; ++mi){
      int off = (wm + mi*16 + lr) * 32 + rdcol;
      ah[mi] = *(const u16x8*)(sAh + off);
      al[mi] = *(const u16x8*)(sAl + off);
    }
    #pragma unroll
    for(int ni = 0; ni < 4; ++ni){
      int off = (wn + ni*16 + lr) * 32 + rdcol;
      u16x8 bh = *(const u16x8*)(sBh + off);
      u16x8 bl = *(const u16x8*)(sBl + off);
      #pragma unroll
      for(int mi = 0; mi < 4; ++mi){
        acc[mi][ni] = mfma16(ah[mi], bh, acc[mi][ni]);
        acc[mi][ni] = mfma16(ah[mi], bl, acc[mi][ni]);
        acc[mi][ni] = mfma16(al[mi], bh, acc[mi][ni]);
      }
    }
  }
  #pragma unroll
  for(int mi = 0; mi < 4; ++mi)
    #pragma unroll
    for(int r = 0; r < 4; ++r){
      long rowoff = (long)(m0 + wm + mi*16 + lg*4 + r) * ldc + n0 + wn + lr;
      #pragma unroll
      for(int ni = 0; ni < 4; ++ni)
        C[rowoff + ni*16] = acc[mi][ni][r];
    }
}

// ---------------- postprocess Q: rmsnorm + rope + log2-scale -> bf16 (B,H,Q,D) -----------
__global__ __launch_bounds__(256) void pp_q(
    const float* __restrict__ Craw, const float* __restrict__ cosb,
    const float* __restrict__ sinb, const float* __restrict__ qw,
    unsigned short* __restrict__ Qb){
  int rid = blockIdx.x * 4 + (threadIdx.x >> 6);
  int lane = threadIdx.x & 63;
  int b = rid >> 15;
  int rem = rid & 32767;
  int q = rem >> 5;
  int h = rem & 31;
  long rowoff = (long)(b * Q_ + q) * NQKV + h * 128;
  float x1 = Craw[rowoff + lane];
  float x2 = Craw[rowoff + 64 + lane];
  float ss = x1*x1 + x2*x2;
  for(int o = 32; o; o >>= 1) ss += __shfl_xor(ss, o);
  float norm = rsqrtf(ss * (1.0f/128.0f) + 1e-6f);
  float xn1 = x1 * norm * qw[lane];
  float xn2 = x2 * norm * qw[64 + lane];
  long co = (long)(b * Q_ + q) * 128;
  float c1 = cosb[co + lane],      s1 = sinb[co + lane];
  float c2 = cosb[co + 64 + lane], s2 = sinb[co + 64 + lane];
  float o1 = (xn1 * c1 - xn2 * s1) * QSCALE;
  float o2 = (xn2 * c2 + xn1 * s2) * QSCALE;
  long dst = ((long)(b * H_ + h) * Q_ + q) * 128;
  Qb[dst + lane] = f2bf(o1);
  Qb[dst + 64 + lane] = f2bf(o2);
}

// ---------------- postprocess K,V: k rmsnorm+rope single bf16; v -> VT scatter -----------
__global__ __launch_bounds__(256) void pp_kv(
    const float* __restrict__ Craw, const float* __restrict__ cosb,
    const float* __restrict__ sinb, const float* __restrict__ kw,
    unsigned short* __restrict__ Kb, unsigned short* __restrict__ VT){
  int rid = blockIdx.x * 4 + (threadIdx.x >> 6);
  int lane = threadIdx.x & 63;
  int b = rid >> 13;
  int rem = rid & 8191;
  int q = rem >> 3;
  int kv = rem & 7;
  int bkv = b * KV_ + kv;
  long rowoff = (long)(b * Q_ + q) * NQKV;
  float x1 = Craw[rowoff + 4096 + kv*128 + lane];
  float x2 = Craw[rowoff + 4096 + kv*128 + 64 + lane];
  float ss = x1*x1 + x2*x2;
  for(int o = 32; o; o >>= 1) ss += __shfl_xor(ss, o);
  float norm = rsqrtf(ss * (1.0f/128.0f) + 1e-6f);
  float xn1 = x1 * norm * kw[lane];
  float xn2 = x2 * norm * kw[64 + lane];
  long co = (long)(b * Q_ + q) * 128;
  float c1 = cosb[co + lane],      s1 = sinb[co + lane];
  float c2 = cosb[co + 64 + lane], s2 = sinb[co + 64 + lane];
  long dst = ((long)bkv * S_ + P_ + q) * 128;
  Kb[dst + lane]      = f2bf(xn1 * c1 - xn2 * s1);
  Kb[dst + 64 + lane] = f2bf(xn2 * c2 + xn1 * s2);
  float v1 = Craw[rowoff + 5120 + kv*128 + lane];
  float v2 = Craw[rowoff + 5120 + kv*128 + 64 + lane];
  VT[((long)bkv * 128 + lane) * S_ + P_ + q]      = f2bf(v1);
  VT[((long)bkv * 128 + 64 + lane) * S_ + P_ + q] = f2bf(v2);
}

// ---------------- flash attention: swapped-QK, log2 softmax, dbuf 32-key tiles -----------
// per block: 128 q (4 waves x 32 q). LDS: K dbuf 16K + V dbuf 16K + P 10K = 42KB.
#define KVB 32
#define PSL 40
__global__ __launch_bounds__(256) void attn(
    const unsigned short* __restrict__ Qg, const unsigned short* __restrict__ Kg,
    const unsigned short* __restrict__ VTg,
    unsigned short* __restrict__ Ohi, unsigned short* __restrict__ Olo){
  __shared__ __align__(16) unsigned short Ks[2][KVB*128];
  __shared__ __align__(16) unsigned short Vs[2][128*KVB];
  __shared__ __align__(16) unsigned short Ps[4][32*PSL];
  int tid = threadIdx.x;
  int b = blockIdx.z, h = blockIdx.y, q0 = blockIdx.x * 128;
  int kvh = h >> 2;
  int w = tid >> 6, lane = tid & 63, lr = lane & 15, lg = lane >> 4;
  int q0w = q0 + w * 32;
  // Q fragments (B-operand: col = q = lane&15, k = lg*8+j)
  u16x8 qh[2][4];
  #pragma unroll
  for(int mi = 0; mi < 2; ++mi){
    long qbase = ((long)(b * H_ + h) * Q_ + q0w + mi*16 + lr) * 128;
    #pragma unroll
    for(int c = 0; c < 4; ++c)
      qh[mi][c] = *(const u16x8*)(Qg + qbase + c*32 + lg*8);
  }
  f32x4 zero = {0.f,0.f,0.f,0.f};
  f32x4 o[2][8];
  #pragma unroll
  for(int mi = 0; mi < 2; ++mi)
    #pragma unroll
    for(int i = 0; i < 8; ++i) o[mi][i] = zero;
  float m[2] = {-3.0e38f, -3.0e38f};
  float l[2] = {0.f, 0.f};
  long kb  = (long)(b * KV_ + kvh) * S_ * 128;
  long vb0 = (long)(b * KV_ + kvh) * 128 * (long)S_;
  int ntiles = 100 + blockIdx.x * 4;
  // staging constants: K slot L -> row r=L>>4, chunk (L&15)^(r&7) of the key-row
  //                    V slot L -> d=L>>2, s-chunk (L&3)^(d&3)^((d>>2)&3)
  int koff[2], voff[2], ldst[2];
  #pragma unroll
  for(int i = 0; i < 2; ++i){
    int L = (w*2 + i)*64 + lane;
    ldst[i] = L * 8;
    int r = L >> 4, c8 = (L & 15) ^ (r & 7);
    koff[i] = r*128 + c8*8;
    int d = L >> 2, sc = (L & 3) ^ (d & 3) ^ ((d >> 2) & 3);
    voff[i] = d*S_ + sc*8;
  }
  // prologue: stage tile 0
  {
    const unsigned short* kg = Kg + kb;
    const unsigned short* vg = VTg + vb0;
    #pragma unroll
    for(int i = 0; i < 2; ++i){
      gl16(kg + koff[i], &Ks[0][ldst[i]]);
      gl16(vg + voff[i], &Vs[0][ldst[i]]);
    }
  }
  __syncthreads();

  int lr7 = lr & 7;
  int vsc读 = 0; (void)vsc读;
  for(int t = 0; t < ntiles; ++t){
    int cur = t & 1;
    if(t + 1 < ntiles){
      int s1 = (t + 1) * KVB;
      const unsigned short* kg = Kg + kb + (long)s1 * 128;
      const unsigned short* vg = VTg + vb0 + s1;
      #pragma unroll
      for(int i = 0; i < 2; ++i){
        gl16(kg + koff[i], &Ks[cur^1][ldst[i]]);
        gl16(vg + voff[i], &Vs[cur^1][ldst[i]]);
      }
    }
    int s0 = t * KVB;
    if(s0 <= P_ + q0w + 31){
      // ---- QK^T (swapped: A=K rows=keys, B=Q cols=queries) ----
      f32x4 pacc[2][2];
      pacc[0][0] = zero; pacc[0][1] = zero; pacc[1][0] = zero; pacc[1][1] = zero;
      #pragma unroll
      for(int c = 0; c < 4; ++c)
        #pragma unroll
        for(int ni = 0; ni < 2; ++ni){
          u16x8 kh = *(const u16x8*)(&Ks[cur][(ni*16 + lr)*128 + (((c*4 + lg) ^ lr7) << 3)]);
          pacc[0][ni] = mfma16(kh, qh[0][c], pacc[0][ni]);
          pacc[1][ni] = mfma16(kh, qh[1][c], pacc[1][ni]);
        }
      // ---- causal mask (lane holds q=lr, keys ni*16+lg*4+r) ----
      if(s0 + KVB - 1 > P_ + q0w){
        #pragma unroll
        for(int mi = 0; mi < 2; ++mi){
          int qrow = q0w + mi*16 + lr;
          #pragma unroll
          for(int ni = 0; ni < 2; ++ni)
            #pragma unroll
            for(int r = 0; r < 4; ++r){
              int skey = s0 + ni*16 + lg*4 + r;
              if(skey > P_ + qrow) pacc[mi][ni][r] = -1e30f;
            }
        }
      }
      // ---- per-q max: 7 in-lane fmax + 2 shfl ----
      float tmx[2];
      #pragma unroll
      for(int mi = 0; mi < 2; ++mi){
        float t0 = fmaxf(fmaxf(pacc[mi][0][0], pacc[mi][0][1]),
                         fmaxf(pacc[mi][0][2], pacc[mi][0][3]));
        float t1 = fmaxf(fmaxf(pacc[mi][1][0], pacc[mi][1][1]),
                         fmaxf(pacc[mi][1][2], pacc[mi][1][3]));
        float tm = fmaxf(t0, t1);
        tm = fmaxf(tm, __shfl_xor(tm, 16));
        tm = fmaxf(tm, __shfl_xor(tm, 32));
        tmx[mi] = tm;
      }
      // ---- deferred rescale (T13, log2 units, P <= 2^8) ----
      int need = (tmx[0] > m[0] + 8.f) | (tmx[1] > m[1] + 8.f);
      if(__any(need)){
        #pragma unroll
        for(int mi = 0; mi < 2; ++mi){
          float mn = fmaxf(m[mi], tmx[mi]);
          float fac = exp2f(m[mi] - mn);
          m[mi] = mn; l[mi] *= fac;
          #pragma unroll
          for(int r = 0; r < 4; ++r){
            float fr = __shfl(fac, (lg << 4) | (lg*4 + r));
            #pragma unroll
            for(int ni = 0; ni < 8; ++ni) o[mi][ni][r] *= fr;
          }
        }
      }
      // ---- p = exp2(s - m), row-sum, pack to bf16, store P [q][k] ----
      #pragma unroll
      for(int mi = 0; mi < 2; ++mi){
        float rs = 0.f;
        #pragma unroll
        for(int ni = 0; ni < 2; ++ni){
          float p0 = exp2f(pacc[mi][ni][0] - m[mi]);
          float p1 = exp2f(pacc[mi][ni][1] - m[mi]);
          float p2 = exp2f(pacc[mi][ni][2] - m[mi]);
          float p3 = exp2f(pacc[mi][ni][3] - m[mi]);
          rs += (p0 + p1) + (p2 + p3);
          uint2 pw; pw.x = pk2bf(p0, p1); pw.y = pk2bf(p2, p3);
          *(uint2*)(&Ps[w][(mi*16 + lr)*PSL + ni*16 + lg*4]) = pw;
        }
        rs += __shfl_xor(rs, 16);
        rs += __shfl_xor(rs, 32);
        l[mi] += rs;
      }
      // ---- PV: A = P (rows=q), B = V^T (cols=d) ----
      u16x8 pa0 = *(const u16x8*)(&Ps[w][lr*PSL + lg*8]);
      u16x8 pa1 = *(const u16x8*)(&Ps[w][(16 + lr)*PSL + lg*8]);
      #pragma unroll
      for(int ni = 0; ni < 8; ++ni){
        int d = ni*16 + lr;
        int scs = lg ^ (lr & 3) ^ ((lr >> 2) & 3);
        u16x8 vbf = *(const u16x8*)(&Vs[cur][d*32 + (scs << 3)]);
        o[0][ni] = mfma16(pa0, vbf, o[0][ni]);
        o[1][ni] = mfma16(pa1, vbf, o[1][ni]);
      }
    }
    __syncthreads();
  }
  // ---- epilogue: divide by l, write hi/lo bf16 ----
  #pragma unroll
  for(int mi = 0; mi < 2; ++mi){
    float linv = 1.0f / l[mi];
    #pragma unroll
    for(int r = 0; r < 4; ++r){
      float li = __shfl(linv, (lg << 4) | (lg*4 + r));
      int qrow = q0w + mi*16 + lg*4 + r;
      long obase = (long)(b * Q_ + qrow) * 4096 + h * 128;
      #pragma unroll
      for(int ni = 0; ni < 8; ++ni){
        float val = o[mi][ni][r] * li;
        unsigned short hh, ll; f2hilo(val, hh, ll);
        Ohi[obase + ni*16 + lr] = hh;
        Olo[obase + ni*16 + lr] = ll;
      }
    }
  }
}

extern "C" void kernel_launch(void* const* d_in, const int* in_sizes, int n_in,
                              void* d_out, int out_size, void* d_ws, size_t ws_size,
                              hipStream_t stream){
  const float* hs   = (const float*)d_in[0];
  const float* cosb = (const float*)d_in[1];
  const float* sinb = (const float*)d_in[2];
  const float* kc   = (const float*)d_in[3];
  const float* vc   = (const float*)d_in[4];
  const float* Wq   = (const float*)d_in[5];
  const float* Wk   = (const float*)d_in[6];
  const float* Wv   = (const float*)d_in[7];
  const float* Wo   = (const float*)d_in[8];
  const float* qw   = (const float*)d_in[9];
  const float* kw   = (const float*)d_in[10];
  char* ws = (char*)d_ws;
  float* Craw          = (float*)ws;                        // 50.3 MB, dead after pp_*
  unsigned short* OH   = (unsigned short*)ws;               // alias over dead Craw
  unsigned short* OL   = (unsigned short*)(ws + 16777216);
  unsigned short* WTh  = (unsigned short*)(ws + 50331648);
  unsigned short* WTl  = (unsigned short*)(ws + 100663296);
  unsigned short* WoTh = (unsigned short*)(ws + 50331648);  // over dead WT
  unsigned short* WoTl = (unsigned short*)(ws + 83886080);
  unsigned short* AH   = (unsigned short*)(ws + 150994944);
  unsigned short* AL   = (unsigned short*)(ws + 167772160);
  unsigned short* QB   = (unsigned short*)(ws + 150994944); // over dead AH
  unsigned short* KB   = (unsigned short*)(ws + 184549376);
  unsigned short* VT   = (unsigned short*)(ws + 218103808);
  float* Out = (float*)d_out;

  convert_hs<<<dim3(2048), dim3(256), 0, stream>>>(hs, AH, AL, (B_*Q_*HID_)/4);
  convert_wt<<<dim3(64,64), dim3(256), 0, stream>>>(Wq, WTh, WTl, 4096, 0);
  convert_wt<<<dim3(16,64), dim3(256), 0, stream>>>(Wk, WTh, WTl, 1024, 4096);
  convert_wt<<<dim3(16,64), dim3(256), 0, stream>>>(Wv, WTh, WTl, 1024, 5120);
  cache_k<<<dim3(2048), dim3(256), 0, stream>>>(kc, KB);
  cache_vt<<<dim3(48, 16), dim3(256), 0, stream>>>(vc, VT);
  gemm_hilo<<<dim3(768), dim3(256), 0, stream>>>(AH, AL, WTh, WTl, Craw, 48, NQKV);
  pp_q<<<dim3(16384), dim3(256), 0, stream>>>(Craw, cosb, sinb, qw, QB);
  pp_kv<<<dim3(4096), dim3(256), 0, stream>>>(Craw, cosb, sinb, kw, KB, VT);
  convert_wt<<<dim3(64,64), dim3(256), 0, stream>>>(Wo, WoTh, WoTl, 4096, 0);
  attn<<<dim3(8, 32, 2), dim3(256), 0, stream>>>(QB, KB, VT, OH, OL);
  gemm_hilo<<<dim3(512), dim3(256), 0, stream>>>(OH, OL, WoTh, WoTl, Out, 32, 4096);
}

// Round 5
// 564.861 us; speedup vs baseline: 3.8149x; 1.6785x over previous
//
#include <hip/hip_runtime.h>
#include <hip/hip_bf16.h>

#define B_ 2
#define Q_ 1024
#define P_ 3072
#define HID_ 4096
#define H_ 32
#define KV_ 8
#define D_ 128
#define S_ 4096
#define NQKV 6144
// 1/sqrt(128) * log2(e)  (softmax runs in log2 domain)
#define QSCALE 0.1275174432f

typedef __attribute__((ext_vector_type(4))) float f32x4;
typedef __attribute__((ext_vector_type(8))) unsigned short u16x8;
typedef __attribute__((ext_vector_type(4))) unsigned short u16x4;
typedef __attribute__((ext_vector_type(8))) __bf16 bf16x8;

__device__ __forceinline__ unsigned short f2bf(float f){
  unsigned u = __builtin_bit_cast(unsigned, f);
  unsigned r = (u + 0x7FFFu + ((u >> 16) & 1u)) >> 16;
  return (unsigned short)r;
}
__device__ __forceinline__ unsigned pk2bf(float lo, float hi){
  unsigned r;
  asm("v_cvt_pk_bf16_f32 %0, %1, %2" : "=v"(r) : "v"(lo), "v"(hi));
  return r;
}
__device__ __forceinline__ f32x4 mfma16(u16x8 a, u16x8 b, f32x4 c){
  return __builtin_amdgcn_mfma_f32_16x16x32_bf16(
      __builtin_bit_cast(bf16x8, a), __builtin_bit_cast(bf16x8, b), c, 0, 0, 0);
}
typedef const __attribute__((address_space(1))) void* gp1_t;
typedef __attribute__((address_space(3))) void* lp3_t;
__device__ __forceinline__ void gl16(const unsigned short* g, unsigned short* l){
  __builtin_amdgcn_global_load_lds((gp1_t)g, (lp3_t)l, 16, 0, 0);
}

// ---------------- convert hidden states: fp32 -> bf16 ------------------------------------
__global__ __launch_bounds__(256) void convert_hs(
    const float* __restrict__ X, unsigned short* __restrict__ Hh, int total4){
  for(int i4 = blockIdx.x * 256 + threadIdx.x; i4 < total4; i4 += gridDim.x * 256){
    long i = (long)i4 * 4;
    float4 x = *(const float4*)(X + i);
    *(u16x4*)(Hh + i) = (u16x4){f2bf(x.x), f2bf(x.y), f2bf(x.z), f2bf(x.w)};
  }
}

// ---------------- convert weights: W[k][n] fp32 -> WT[n_off+n][k] bf16 (transpose) -------
__global__ __launch_bounds__(256) void convert_wt(
    const float* __restrict__ W, unsigned short* __restrict__ Th, int ldn, int n_off){
  __shared__ float tile[64][65];
  int k0 = blockIdx.y * 64, n0 = blockIdx.x * 64;
  int tid = threadIdx.x;
  int r = tid >> 4, c = (tid & 15) * 4;
  #pragma unroll
  for(int j = 0; j < 4; ++j){
    float4 v = *(const float4*)(W + (long)(k0 + r + j*16) * ldn + n0 + c);
    tile[r + j*16][c] = v.x; tile[r + j*16][c+1] = v.y;
    tile[r + j*16][c+2] = v.z; tile[r + j*16][c+3] = v.w;
  }
  __syncthreads();
  #pragma unroll
  for(int j = 0; j < 4; ++j){
    int n = r + j*16;
    long o = (long)(n_off + n0 + n) * 4096 + k0 + c;
    *(u16x4*)(Th + o) = (u16x4){f2bf(tile[c][n]), f2bf(tile[c+1][n]),
                                f2bf(tile[c+2][n]), f2bf(tile[c+3][n])};
  }
}

// ---------------- cache K: fp32 (B,KV,P,D) -> single bf16 at s in [0,P) ------------------
__global__ __launch_bounds__(256) void cache_k(
    const float* __restrict__ kc, unsigned short* __restrict__ Kb){
  const int PD = P_ * D_;
  const long SD = (long)S_ * D_;
  int total4 = (B_ * KV_ * PD) >> 2;
  for(int i4 = blockIdx.x * 256 + threadIdx.x; i4 < total4; i4 += gridDim.x * 256){
    long i = (long)i4 * 4;
    int bkv = (int)(i / PD);
    int rem = (int)(i - (long)bkv * PD);
    long dst = (long)bkv * SD + rem;
    float4 k4 = *(const float4*)(kc + i);
    *(u16x4*)(Kb + dst) = (u16x4){f2bf(k4.x), f2bf(k4.y), f2bf(k4.z), f2bf(k4.w)};
  }
}

// ---------------- cache V transpose: fp32 (B,KV,P,D) -> VT bf16 [b,kv][d][s] -------------
__global__ __launch_bounds__(256) void cache_vt(
    const float* __restrict__ vc, unsigned short* __restrict__ VT){
  __shared__ unsigned short T[128][72];
  int bkv = blockIdx.y;
  int s0 = blockIdx.x * 64;
  int tid = threadIdx.x;
  int r = tid >> 2, dblk = (tid & 3) * 32;
  const float* src = vc + ((long)bkv * P_ + s0 + r) * 128 + dblk;
  #pragma unroll
  for(int u = 0; u < 8; ++u){
    float4 v = *(const float4*)(src + u*4);
    T[dblk + u*4 + 0][r] = f2bf(v.x);
    T[dblk + u*4 + 1][r] = f2bf(v.y);
    T[dblk + u*4 + 2][r] = f2bf(v.z);
    T[dblk + u*4 + 3][r] = f2bf(v.w);
  }
  __syncthreads();
  int d = tid >> 1, sh = (tid & 1) * 32;
  unsigned short* dst = VT + ((long)bkv * 128 + d) * S_ + s0 + sh;
  #pragma unroll
  for(int u = 0; u < 4; ++u){
    u16x8 v;
    #pragma unroll
    for(int j = 0; j < 8; ++j) v[j] = T[d][sh + u*8 + j];
    *(u16x8*)(dst + u*8) = v;
  }
}

// ---------------- single-plane bf16 GEMM (m97 structure, swizzled gl16 staging) ----------
__global__ __launch_bounds__(256) void gemm_bf16(
    const unsigned short* __restrict__ Ag, const unsigned short* __restrict__ Bg,
    float* __restrict__ C, int nbx, int ldc){
  __shared__ __align__(16) unsigned short sA[4096], sB[4096];
  int tid = threadIdx.x;
  int nwg = nbx * 16;
  int lin = blockIdx.x;
  int cpx = nwg >> 3;
  int swz = (lin & 7) * cpx + (lin >> 3);   // XCD swizzle (nwg % 8 == 0)
  int bx = swz % nbx, by = swz / nbx;
  int m0 = by * 128, n0 = bx * 128;
  int lane = tid & 63, w = tid >> 6;
  int lr = lane & 15, lg = lane >> 4;
  int wm = (w >> 1) * 64, wn = (w & 1) * 64;
  int rowi = w * 16 + (lane >> 2);
  int cchunk = ((lane & 3) ^ ((lane >> 3) & 3)) << 3;
  const unsigned short* aP = Ag + (long)(m0 + rowi) * 4096 + cchunk;
  const unsigned short* bP = Bg + (long)(n0 + rowi) * 4096 + cchunk;
  const int step2 = 64 * 4096;
  unsigned short* dA = sA + w * 512;
  unsigned short* dB = sB + w * 512;
  int rdcol = (lg * 8) ^ (((lr >> 1) & 3) << 3);
  f32x4 zero = {0.f,0.f,0.f,0.f};
  f32x4 acc[4][4];
  #pragma unroll
  for(int mi=0;mi<4;++mi)
    #pragma unroll
    for(int ni=0;ni<4;++ni) acc[mi][ni] = zero;

  for(int kt = 0; kt < 128; ++kt){
    int kk = kt * 32;
    __syncthreads();
    gl16(aP + kk, dA);  gl16(aP + step2 + kk, dA + 2048);
    gl16(bP + kk, dB);  gl16(bP + step2 + kk, dB + 2048);
    __syncthreads();
    u16x8 ah[4];
    #pragma unroll
    for(int mi = 0; mi < 4; ++mi)
      ah[mi] = *(const u16x8*)(sA + (wm + mi*16 + lr) * 32 + rdcol);
    #pragma unroll
    for(int ni = 0; ni < 4; ++ni){
      u16x8 bh = *(const u16x8*)(sB + (wn + ni*16 + lr) * 32 + rdcol);
      #pragma unroll
      for(int mi = 0; mi < 4; ++mi)
        acc[mi][ni] = mfma16(ah[mi], bh, acc[mi][ni]);
    }
  }
  #pragma unroll
  for(int mi = 0; mi < 4; ++mi)
    #pragma unroll
    for(int r = 0; r < 4; ++r){
      long rowoff = (long)(m0 + wm + mi*16 + lg*4 + r) * ldc + n0 + wn + lr;
      #pragma unroll
      for(int ni = 0; ni < 4; ++ni)
        C[rowoff + ni*16] = acc[mi][ni][r];
    }
}

// ---------------- postprocess Q: rmsnorm + rope + log2-scale -> bf16 (B,H,Q,D) -----------
__global__ __launch_bounds__(256) void pp_q(
    const float* __restrict__ Craw, const float* __restrict__ cosb,
    const float* __restrict__ sinb, const float* __restrict__ qw,
    unsigned short* __restrict__ Qb){
  int rid = blockIdx.x * 4 + (threadIdx.x >> 6);
  int lane = threadIdx.x & 63;
  int b = rid >> 15;
  int rem = rid & 32767;
  int q = rem >> 5;
  int h = rem & 31;
  long rowoff = (long)(b * Q_ + q) * NQKV + h * 128;
  float x1 = Craw[rowoff + lane];
  float x2 = Craw[rowoff + 64 + lane];
  float ss = x1*x1 + x2*x2;
  for(int o = 32; o; o >>= 1) ss += __shfl_xor(ss, o);
  float norm = rsqrtf(ss * (1.0f/128.0f) + 1e-6f);
  float xn1 = x1 * norm * qw[lane];
  float xn2 = x2 * norm * qw[64 + lane];
  long co = (long)(b * Q_ + q) * 128;
  float c1 = cosb[co + lane],      s1 = sinb[co + lane];
  float c2 = cosb[co + 64 + lane], s2 = sinb[co + 64 + lane];
  float o1 = (xn1 * c1 - xn2 * s1) * QSCALE;
  float o2 = (xn2 * c2 + xn1 * s2) * QSCALE;
  long dst = ((long)(b * H_ + h) * Q_ + q) * 128;
  Qb[dst + lane] = f2bf(o1);
  Qb[dst + 64 + lane] = f2bf(o2);
}

// ---------------- postprocess K,V: k rmsnorm+rope single bf16; v -> VT scatter -----------
__global__ __launch_bounds__(256) void pp_kv(
    const float* __restrict__ Craw, const float* __restrict__ cosb,
    const float* __restrict__ sinb, const float* __restrict__ kw,
    unsigned short* __restrict__ Kb, unsigned short* __restrict__ VT){
  int rid = blockIdx.x * 4 + (threadIdx.x >> 6);
  int lane = threadIdx.x & 63;
  int b = rid >> 13;
  int rem = rid & 8191;
  int q = rem >> 3;
  int kv = rem & 7;
  int bkv = b * KV_ + kv;
  long rowoff = (long)(b * Q_ + q) * NQKV;
  float x1 = Craw[rowoff + 4096 + kv*128 + lane];
  float x2 = Craw[rowoff + 4096 + kv*128 + 64 + lane];
  float ss = x1*x1 + x2*x2;
  for(int o = 32; o; o >>= 1) ss += __shfl_xor(ss, o);
  float norm = rsqrtf(ss * (1.0f/128.0f) + 1e-6f);
  float xn1 = x1 * norm * kw[lane];
  float xn2 = x2 * norm * kw[64 + lane];
  long co = (long)(b * Q_ + q) * 128;
  float c1 = cosb[co + lane],      s1 = sinb[co + lane];
  float c2 = cosb[co + 64 + lane], s2 = sinb[co + 64 + lane];
  long dst = ((long)bkv * S_ + P_ + q) * 128;
  Kb[dst + lane]      = f2bf(xn1 * c1 - xn2 * s1);
  Kb[dst + 64 + lane] = f2bf(xn2 * c2 + xn1 * s2);
  float v1 = Craw[rowoff + 5120 + kv*128 + lane];
  float v2 = Craw[rowoff + 5120 + kv*128 + 64 + lane];
  VT[((long)bkv * 128 + lane) * S_ + P_ + q]      = f2bf(v1);
  VT[((long)bkv * 128 + 64 + lane) * S_ + P_ + q] = f2bf(v2);
}

// ---------------- flash attention: swapped-QK, log2 softmax, dbuf 32-key tiles -----------
#define KVB 32
#define PSL 40
__global__ __launch_bounds__(256) void attn(
    const unsigned short* __restrict__ Qg, const unsigned short* __restrict__ Kg,
    const unsigned short* __restrict__ VTg, unsigned short* __restrict__ Og){
  __shared__ __align__(16) unsigned short Ks[2][KVB*128];
  __shared__ __align__(16) unsigned short Vs[2][128*KVB];
  __shared__ __align__(16) unsigned short Ps[4][32*PSL];
  int tid = threadIdx.x;
  int b = blockIdx.z, h = blockIdx.y, q0 = blockIdx.x * 128;
  int kvh = h >> 2;
  int w = tid >> 6, lane = tid & 63, lr = lane & 15, lg = lane >> 4;
  int q0w = q0 + w * 32;
  u16x8 qh[2][4];
  #pragma unroll
  for(int mi = 0; mi < 2; ++mi){
    long qbase = ((long)(b * H_ + h) * Q_ + q0w + mi*16 + lr) * 128;
    #pragma unroll
    for(int c = 0; c < 4; ++c)
      qh[mi][c] = *(const u16x8*)(Qg + qbase + c*32 + lg*8);
  }
  f32x4 zero = {0.f,0.f,0.f,0.f};
  f32x4 o[2][8];
  #pragma unroll
  for(int mi = 0; mi < 2; ++mi)
    #pragma unroll
    for(int i = 0; i < 8; ++i) o[mi][i] = zero;
  float m[2] = {-3.0e38f, -3.0e38f};
  float l[2] = {0.f, 0.f};
  long kb  = (long)(b * KV_ + kvh) * S_ * 128;
  long vb0 = (long)(b * KV_ + kvh) * 128 * (long)S_;
  int ntiles = 100 + blockIdx.x * 4;
  int koff[2], voff[2], ldst[2];
  #pragma unroll
  for(int i = 0; i < 2; ++i){
    int L = (w*2 + i)*64 + lane;
    ldst[i] = L * 8;
    int r = L >> 4, c8 = (L & 15) ^ (r & 7);
    koff[i] = r*128 + c8*8;
    int d = L >> 2, sc = (L & 3) ^ (d & 3) ^ ((d >> 2) & 3);
    voff[i] = d*S_ + sc*8;
  }
  {
    const unsigned short* kg = Kg + kb;
    const unsigned short* vg = VTg + vb0;
    #pragma unroll
    for(int i = 0; i < 2; ++i){
      gl16(kg + koff[i], &Ks[0][ldst[i]]);
      gl16(vg + voff[i], &Vs[0][ldst[i]]);
    }
  }
  __syncthreads();

  int lr7 = lr & 7;
  for(int t = 0; t < ntiles; ++t){
    int cur = t & 1;
    if(t + 1 < ntiles){
      int s1 = (t + 1) * KVB;
      const unsigned short* kg = Kg + kb + (long)s1 * 128;
      const unsigned short* vg = VTg + vb0 + s1;
      #pragma unroll
      for(int i = 0; i < 2; ++i){
        gl16(kg + koff[i], &Ks[cur^1][ldst[i]]);
        gl16(vg + voff[i], &Vs[cur^1][ldst[i]]);
      }
    }
    int s0 = t * KVB;
    if(s0 <= P_ + q0w + 31){
      f32x4 pacc[2][2];
      pacc[0][0] = zero; pacc[0][1] = zero; pacc[1][0] = zero; pacc[1][1] = zero;
      #pragma unroll
      for(int c = 0; c < 4; ++c)
        #pragma unroll
        for(int ni = 0; ni < 2; ++ni){
          u16x8 kh = *(const u16x8*)(&Ks[cur][(ni*16 + lr)*128 + (((c*4 + lg) ^ lr7) << 3)]);
          pacc[0][ni] = mfma16(kh, qh[0][c], pacc[0][ni]);
          pacc[1][ni] = mfma16(kh, qh[1][c], pacc[1][ni]);
        }
      if(s0 + KVB - 1 > P_ + q0w){
        #pragma unroll
        for(int mi = 0; mi < 2; ++mi){
          int qrow = q0w + mi*16 + lr;
          #pragma unroll
          for(int ni = 0; ni < 2; ++ni)
            #pragma unroll
            for(int r = 0; r < 4; ++r){
              int skey = s0 + ni*16 + lg*4 + r;
              if(skey > P_ + qrow) pacc[mi][ni][r] = -1e30f;
            }
        }
      }
      float tmx[2];
      #pragma unroll
      for(int mi = 0; mi < 2; ++mi){
        float t0 = fmaxf(fmaxf(pacc[mi][0][0], pacc[mi][0][1]),
                         fmaxf(pacc[mi][0][2], pacc[mi][0][3]));
        float t1 = fmaxf(fmaxf(pacc[mi][1][0], pacc[mi][1][1]),
                         fmaxf(pacc[mi][1][2], pacc[mi][1][3]));
        float tm = fmaxf(t0, t1);
        tm = fmaxf(tm, __shfl_xor(tm, 16));
        tm = fmaxf(tm, __shfl_xor(tm, 32));
        tmx[mi] = tm;
      }
      int need = (tmx[0] > m[0] + 8.f) | (tmx[1] > m[1] + 8.f);
      if(__any(need)){
        #pragma unroll
        for(int mi = 0; mi < 2; ++mi){
          float mn = fmaxf(m[mi], tmx[mi]);
          float fac = exp2f(m[mi] - mn);
          m[mi] = mn; l[mi] *= fac;
          #pragma unroll
          for(int r = 0; r < 4; ++r){
            float fr = __shfl(fac, (lg << 4) | (lg*4 + r));
            #pragma unroll
            for(int ni = 0; ni < 8; ++ni) o[mi][ni][r] *= fr;
          }
        }
      }
      #pragma unroll
      for(int mi = 0; mi < 2; ++mi){
        float rs = 0.f;
        #pragma unroll
        for(int ni = 0; ni < 2; ++ni){
          float p0 = exp2f(pacc[mi][ni][0] - m[mi]);
          float p1 = exp2f(pacc[mi][ni][1] - m[mi]);
          float p2 = exp2f(pacc[mi][ni][2] - m[mi]);
          float p3 = exp2f(pacc[mi][ni][3] - m[mi]);
          rs += (p0 + p1) + (p2 + p3);
          uint2 pw; pw.x = pk2bf(p0, p1); pw.y = pk2bf(p2, p3);
          *(uint2*)(&Ps[w][(mi*16 + lr)*PSL + ni*16 + lg*4]) = pw;
        }
        rs += __shfl_xor(rs, 16);
        rs += __shfl_xor(rs, 32);
        l[mi] += rs;
      }
      u16x8 pa0 = *(const u16x8*)(&Ps[w][lr*PSL + lg*8]);
      u16x8 pa1 = *(const u16x8*)(&Ps[w][(16 + lr)*PSL + lg*8]);
      #pragma unroll
      for(int ni = 0; ni < 8; ++ni){
        int d = ni*16 + lr;
        int scs = lg ^ (lr & 3) ^ ((lr >> 2) & 3);
        u16x8 vbf = *(const u16x8*)(&Vs[cur][d*32 + (scs << 3)]);
        o[0][ni] = mfma16(pa0, vbf, o[0][ni]);
        o[1][ni] = mfma16(pa1, vbf, o[1][ni]);
      }
    }
    __syncthreads();
  }
  #pragma unroll
  for(int mi = 0; mi < 2; ++mi){
    float linv = 1.0f / l[mi];
    #pragma unroll
    for(int r = 0; r < 4; ++r){
      float li = __shfl(linv, (lg << 4) | (lg*4 + r));
      int qrow = q0w + mi*16 + lg*4 + r;
      long obase = (long)(b * Q_ + qrow) * 4096 + h * 128;
      #pragma unroll
      for(int ni = 0; ni < 8; ++ni)
        Og[obase + ni*16 + lr] = f2bf(o[mi][ni][r] * li);
    }
  }
}

extern "C" void kernel_launch(void* const* d_in, const int* in_sizes, int n_in,
                              void* d_out, int out_size, void* d_ws, size_t ws_size,
                              hipStream_t stream){
  const float* hs   = (const float*)d_in[0];
  const float* cosb = (const float*)d_in[1];
  const float* sinb = (const float*)d_in[2];
  const float* kc   = (const float*)d_in[3];
  const float* vc   = (const float*)d_in[4];
  const float* Wq   = (const float*)d_in[5];
  const float* Wk   = (const float*)d_in[6];
  const float* Wv   = (const float*)d_in[7];
  const float* Wo   = (const float*)d_in[8];
  const float* qw   = (const float*)d_in[9];
  const float* kw   = (const float*)d_in[10];
  char* ws = (char*)d_ws;
  float* Craw          = (float*)ws;                        // 50.3 MB, dead after pp_*
  unsigned short* OH   = (unsigned short*)ws;               // alias over dead Craw
  unsigned short* WTh  = (unsigned short*)(ws + 50331648);  // 6144x4096 bf16
  unsigned short* WoTh = (unsigned short*)(ws + 50331648);  // over dead WTh
  unsigned short* AH   = (unsigned short*)(ws + 150994944);
  unsigned short* QB   = (unsigned short*)(ws + 150994944); // over dead AH
  unsigned short* KB   = (unsigned short*)(ws + 184549376);
  unsigned short* VT   = (unsigned short*)(ws + 218103808);
  float* Out = (float*)d_out;

  convert_hs<<<dim3(2048), dim3(256), 0, stream>>>(hs, AH, (B_*Q_*HID_)/4);
  convert_wt<<<dim3(64,64), dim3(256), 0, stream>>>(Wq, WTh, 4096, 0);
  convert_wt<<<dim3(16,64), dim3(256), 0, stream>>>(Wk, WTh, 1024, 4096);
  convert_wt<<<dim3(16,64), dim3(256), 0, stream>>>(Wv, WTh, 1024, 5120);
  cache_k<<<dim3(2048), dim3(256), 0, stream>>>(kc, KB);
  cache_vt<<<dim3(48, 16), dim3(256), 0, stream>>>(vc, VT);
  gemm_bf16<<<dim3(768), dim3(256), 0, stream>>>(AH, WTh, Craw, 48, NQKV);
  pp_q<<<dim3(16384), dim3(256), 0, stream>>>(Craw, cosb, sinb, qw, QB);
  pp_kv<<<dim3(4096), dim3(256), 0, stream>>>(Craw, cosb, sinb, kw, KB, VT);
  convert_wt<<<dim3(64,64), dim3(256), 0, stream>>>(Wo, WoTh, 4096, 0);
  attn<<<dim3(8, 32, 2), dim3(256), 0, stream>>>(QB, KB, VT, OH);
  gemm_bf16<<<dim3(512), dim3(256), 0, stream>>>(OH, WoTh, Out, 32, 4096);
}

// Round 6
// 537.027 us; speedup vs baseline: 4.0127x; 1.0518x over previous
//
#include <hip/hip_runtime.h>
#include <hip/hip_bf16.h>

#define B_ 2
#define Q_ 1024
#define P_ 3072
#define HID_ 4096
#define H_ 32
#define KV_ 8
#define D_ 128
#define S_ 4096
#define NQKV 6144
// 1/sqrt(128) * log2(e)  (softmax runs in log2 domain)
#define QSCALE 0.1275174432f

typedef __attribute__((ext_vector_type(4))) float f32x4;
typedef __attribute__((ext_vector_type(8))) unsigned short u16x8;
typedef __attribute__((ext_vector_type(4))) unsigned short u16x4;
typedef __attribute__((ext_vector_type(8))) __bf16 bf16x8;

__device__ __forceinline__ unsigned short f2bf(float f){
  unsigned u = __builtin_bit_cast(unsigned, f);
  unsigned r = (u + 0x7FFFu + ((u >> 16) & 1u)) >> 16;
  return (unsigned short)r;
}
__device__ __forceinline__ unsigned pk2bf(float lo, float hi){
  unsigned r;
  asm("v_cvt_pk_bf16_f32 %0, %1, %2" : "=v"(r) : "v"(lo), "v"(hi));
  return r;
}
__device__ __forceinline__ f32x4 mfma16(u16x8 a, u16x8 b, f32x4 c){
  return __builtin_amdgcn_mfma_f32_16x16x32_bf16(
      __builtin_bit_cast(bf16x8, a), __builtin_bit_cast(bf16x8, b), c, 0, 0, 0);
}
typedef const __attribute__((address_space(1))) void* gp1_t;
typedef __attribute__((address_space(3))) void* lp3_t;
__device__ __forceinline__ void gl16(const unsigned short* g, unsigned short* l){
  __builtin_amdgcn_global_load_lds((gp1_t)g, (lp3_t)l, 16, 0, 0);
}

// ---------------- convert hidden states: fp32 -> bf16 ------------------------------------
__global__ __launch_bounds__(256) void convert_hs(
    const float* __restrict__ X, unsigned short* __restrict__ Hh, int total4){
  for(int i4 = blockIdx.x * 256 + threadIdx.x; i4 < total4; i4 += gridDim.x * 256){
    long i = (long)i4 * 4;
    float4 x = *(const float4*)(X + i);
    *(u16x4*)(Hh + i) = (u16x4){f2bf(x.x), f2bf(x.y), f2bf(x.z), f2bf(x.w)};
  }
}

// ---------------- convert weights: W[k][n] fp32 -> WT[n_off+n][k] bf16 (transpose) -------
__global__ __launch_bounds__(256) void convert_wt(
    const float* __restrict__ W, unsigned short* __restrict__ Th, int ldn, int n_off){
  __shared__ float tile[64][65];
  int k0 = blockIdx.y * 64, n0 = blockIdx.x * 64;
  int tid = threadIdx.x;
  int r = tid >> 4, c = (tid & 15) * 4;
  #pragma unroll
  for(int j = 0; j < 4; ++j){
    float4 v = *(const float4*)(W + (long)(k0 + r + j*16) * ldn + n0 + c);
    tile[r + j*16][c] = v.x; tile[r + j*16][c+1] = v.y;
    tile[r + j*16][c+2] = v.z; tile[r + j*16][c+3] = v.w;
  }
  __syncthreads();
  #pragma unroll
  for(int j = 0; j < 4; ++j){
    int n = r + j*16;
    long o = (long)(n_off + n0 + n) * 4096 + k0 + c;
    *(u16x4*)(Th + o) = (u16x4){f2bf(tile[c][n]), f2bf(tile[c+1][n]),
                                f2bf(tile[c+2][n]), f2bf(tile[c+3][n])};
  }
}

// ---------------- cache K: fp32 (B,KV,P,D) -> single bf16 at s in [0,P) ------------------
__global__ __launch_bounds__(256) void cache_k(
    const float* __restrict__ kc, unsigned short* __restrict__ Kb){
  const int PD = P_ * D_;
  const long SD = (long)S_ * D_;
  int total4 = (B_ * KV_ * PD) >> 2;
  for(int i4 = blockIdx.x * 256 + threadIdx.x; i4 < total4; i4 += gridDim.x * 256){
    long i = (long)i4 * 4;
    int bkv = (int)(i / PD);
    int rem = (int)(i - (long)bkv * PD);
    long dst = (long)bkv * SD + rem;
    float4 k4 = *(const float4*)(kc + i);
    *(u16x4*)(Kb + dst) = (u16x4){f2bf(k4.x), f2bf(k4.y), f2bf(k4.z), f2bf(k4.w)};
  }
}

// ---------------- cache V transpose: fp32 (B,KV,P,D) -> VT bf16 [b,kv][d][s] -------------
__global__ __launch_bounds__(256) void cache_vt(
    const float* __restrict__ vc, unsigned short* __restrict__ VT){
  __shared__ unsigned short T[128][72];
  int bkv = blockIdx.y;
  int s0 = blockIdx.x * 64;
  int tid = threadIdx.x;
  int r = tid >> 2, dblk = (tid & 3) * 32;
  const float* src = vc + ((long)bkv * P_ + s0 + r) * 128 + dblk;
  #pragma unroll
  for(int u = 0; u < 8; ++u){
    float4 v = *(const float4*)(src + u*4);
    T[dblk + u*4 + 0][r] = f2bf(v.x);
    T[dblk + u*4 + 1][r] = f2bf(v.y);
    T[dblk + u*4 + 2][r] = f2bf(v.z);
    T[dblk + u*4 + 3][r] = f2bf(v.w);
  }
  __syncthreads();
  int d = tid >> 1, sh = (tid & 1) * 32;
  unsigned short* dst = VT + ((long)bkv * 128 + d) * S_ + s0 + sh;
  #pragma unroll
  for(int u = 0; u < 4; ++u){
    u16x8 v;
    #pragma unroll
    for(int j = 0; j < 8; ++j) v[j] = T[d][sh + u*8 + j];
    *(u16x8*)(dst + u*8) = v;
  }
}

// ---------------- logit bound: M = 128*QSCALE*max|qw|*max|kw| ----------------------------
__global__ __launch_bounds__(128) void maxw(
    const float* __restrict__ qw, const float* __restrict__ kw, float* __restrict__ M){
  __shared__ float sa[2], sb[2];
  int t = threadIdx.x;
  float a = fabsf(qw[t]), b = fabsf(kw[t]);
  #pragma unroll
  for(int o = 32; o; o >>= 1){
    a = fmaxf(a, __shfl_xor(a, o));
    b = fmaxf(b, __shfl_xor(b, o));
  }
  if((t & 63) == 0){ sa[t >> 6] = a; sb[t >> 6] = b; }
  __syncthreads();
  if(t == 0){
    float mq = fmaxf(sa[0], sa[1]), mk = fmaxf(sb[0], sb[1]);
    M[0] = 128.0f * QSCALE * mq * mk * 1.01f + 0.25f;
  }
}

// ---------------- single-plane bf16 GEMM (m97 structure, swizzled gl16 staging) ----------
__global__ __launch_bounds__(256) void gemm_bf16(
    const unsigned short* __restrict__ Ag, const unsigned short* __restrict__ Bg,
    float* __restrict__ C, int nbx, int ldc){
  __shared__ __align__(16) unsigned short sA[4096], sB[4096];
  int tid = threadIdx.x;
  int nwg = nbx * 16;
  int lin = blockIdx.x;
  int cpx = nwg >> 3;
  int swz = (lin & 7) * cpx + (lin >> 3);   // XCD swizzle (nwg % 8 == 0)
  int bx = swz % nbx, by = swz / nbx;
  int m0 = by * 128, n0 = bx * 128;
  int lane = tid & 63, w = tid >> 6;
  int lr = lane & 15, lg = lane >> 4;
  int wm = (w >> 1) * 64, wn = (w & 1) * 64;
  int rowi = w * 16 + (lane >> 2);
  int cchunk = ((lane & 3) ^ ((lane >> 3) & 3)) << 3;
  const unsigned short* aP = Ag + (long)(m0 + rowi) * 4096 + cchunk;
  const unsigned short* bP = Bg + (long)(n0 + rowi) * 4096 + cchunk;
  const int step2 = 64 * 4096;
  unsigned short* dA = sA + w * 512;
  unsigned short* dB = sB + w * 512;
  int rdcol = (lg * 8) ^ (((lr >> 1) & 3) << 3);
  f32x4 zero = {0.f,0.f,0.f,0.f};
  f32x4 acc[4][4];
  #pragma unroll
  for(int mi=0;mi<4;++mi)
    #pragma unroll
    for(int ni=0;ni<4;++ni) acc[mi][ni] = zero;

  for(int kt = 0; kt < 128; ++kt){
    int kk = kt * 32;
    __syncthreads();
    gl16(aP + kk, dA);  gl16(aP + step2 + kk, dA + 2048);
    gl16(bP + kk, dB);  gl16(bP + step2 + kk, dB + 2048);
    __syncthreads();
    u16x8 ah[4];
    #pragma unroll
    for(int mi = 0; mi < 4; ++mi)
      ah[mi] = *(const u16x8*)(sA + (wm + mi*16 + lr) * 32 + rdcol);
    #pragma unroll
    for(int ni = 0; ni < 4; ++ni){
      u16x8 bh = *(const u16x8*)(sB + (wn + ni*16 + lr) * 32 + rdcol);
      #pragma unroll
      for(int mi = 0; mi < 4; ++mi)
        acc[mi][ni] = mfma16(ah[mi], bh, acc[mi][ni]);
    }
  }
  #pragma unroll
  for(int mi = 0; mi < 4; ++mi)
    #pragma unroll
    for(int r = 0; r < 4; ++r){
      long rowoff = (long)(m0 + wm + mi*16 + lg*4 + r) * ldc + n0 + wn + lr;
      #pragma unroll
      for(int ni = 0; ni < 4; ++ni)
        C[rowoff + ni*16] = acc[mi][ni][r];
    }
}

// ---------------- postprocess Q: rmsnorm + rope + log2-scale -> bf16 (B,H,Q,D) -----------
__global__ __launch_bounds__(256) void pp_q(
    const float* __restrict__ Craw, const float* __restrict__ cosb,
    const float* __restrict__ sinb, const float* __restrict__ qw,
    unsigned short* __restrict__ Qb){
  int rid = blockIdx.x * 4 + (threadIdx.x >> 6);
  int lane = threadIdx.x & 63;
  int b = rid >> 15;
  int rem = rid & 32767;
  int q = rem >> 5;
  int h = rem & 31;
  long rowoff = (long)(b * Q_ + q) * NQKV + h * 128;
  float x1 = Craw[rowoff + lane];
  float x2 = Craw[rowoff + 64 + lane];
  float ss = x1*x1 + x2*x2;
  for(int o = 32; o; o >>= 1) ss += __shfl_xor(ss, o);
  float norm = rsqrtf(ss * (1.0f/128.0f) + 1e-6f);
  float xn1 = x1 * norm * qw[lane];
  float xn2 = x2 * norm * qw[64 + lane];
  long co = (long)(b * Q_ + q) * 128;
  float c1 = cosb[co + lane],      s1 = sinb[co + lane];
  float c2 = cosb[co + 64 + lane], s2 = sinb[co + 64 + lane];
  float o1 = (xn1 * c1 - xn2 * s1) * QSCALE;
  float o2 = (xn2 * c2 + xn1 * s2) * QSCALE;
  long dst = ((long)(b * H_ + h) * Q_ + q) * 128;
  Qb[dst + lane] = f2bf(o1);
  Qb[dst + 64 + lane] = f2bf(o2);
}

// ---------------- postprocess K,V: k rmsnorm+rope single bf16; v -> VT scatter -----------
__global__ __launch_bounds__(256) void pp_kv(
    const float* __restrict__ Craw, const float* __restrict__ cosb,
    const float* __restrict__ sinb, const float* __restrict__ kw,
    unsigned short* __restrict__ Kb, unsigned short* __restrict__ VT){
  int rid = blockIdx.x * 4 + (threadIdx.x >> 6);
  int lane = threadIdx.x & 63;
  int b = rid >> 13;
  int rem = rid & 8191;
  int q = rem >> 3;
  int kv = rem & 7;
  int bkv = b * KV_ + kv;
  long rowoff = (long)(b * Q_ + q) * NQKV;
  float x1 = Craw[rowoff + 4096 + kv*128 + lane];
  float x2 = Craw[rowoff + 4096 + kv*128 + 64 + lane];
  float ss = x1*x1 + x2*x2;
  for(int o = 32; o; o >>= 1) ss += __shfl_xor(ss, o);
  float norm = rsqrtf(ss * (1.0f/128.0f) + 1e-6f);
  float xn1 = x1 * norm * kw[lane];
  float xn2 = x2 * norm * kw[64 + lane];
  long co = (long)(b * Q_ + q) * 128;
  float c1 = cosb[co + lane],      s1 = sinb[co + lane];
  float c2 = cosb[co + 64 + lane], s2 = sinb[co + 64 + lane];
  long dst = ((long)bkv * S_ + P_ + q) * 128;
  Kb[dst + lane]      = f2bf(xn1 * c1 - xn2 * s1);
  Kb[dst + 64 + lane] = f2bf(xn2 * c2 + xn1 * s2);
  float v1 = Craw[rowoff + 5120 + kv*128 + lane];
  float v2 = Craw[rowoff + 5120 + kv*128 + 64 + lane];
  VT[((long)bkv * 128 + lane) * S_ + P_ + q]      = f2bf(v1);
  VT[((long)bkv * 128 + 64 + lane) * S_ + P_ + q] = f2bf(v2);
}

// ---------------- flash attention: fixed-max softmax, key-split x2, dbuf 32-key tiles ----
#define KVB 32
#define PSL 40
__global__ __launch_bounds__(256) void attn(
    const unsigned short* __restrict__ Qg, const unsigned short* __restrict__ Kg,
    const unsigned short* __restrict__ VTg, const float* __restrict__ Mp,
    float* __restrict__ po, float* __restrict__ pl){
  __shared__ __align__(16) unsigned short Ks[2][KVB*128];
  __shared__ __align__(16) unsigned short Vs[2][128*KVB];
  __shared__ __align__(16) unsigned short Ps[4][32*PSL];
  int tid = threadIdx.x;
  int qb = blockIdx.x >> 1, sp = blockIdx.x & 1;
  int b = blockIdx.z, h = blockIdx.y, q0 = qb * 128;
  int kvh = h >> 2;
  int w = tid >> 6, lane = tid & 63, lr = lane & 15, lg = lane >> 4;
  int q0w = q0 + w * 32;
  float Mv = Mp[0];
  u16x8 qh[2][4];
  #pragma unroll
  for(int mi = 0; mi < 2; ++mi){
    long qbase = ((long)(b * H_ + h) * Q_ + q0w + mi*16 + lr) * 128;
    #pragma unroll
    for(int c = 0; c < 4; ++c)
      qh[mi][c] = *(const u16x8*)(Qg + qbase + c*32 + lg*8);
  }
  f32x4 minit = {-Mv, -Mv, -Mv, -Mv};
  f32x4 zero = {0.f,0.f,0.f,0.f};
  f32x4 o[2][8];
  #pragma unroll
  for(int mi = 0; mi < 2; ++mi)
    #pragma unroll
    for(int i = 0; i < 8; ++i) o[mi][i] = zero;
  float l[2] = {0.f, 0.f};
  long kb  = (long)(b * KV_ + kvh) * S_ * 128;
  long vb0 = (long)(b * KV_ + kvh) * 128 * (long)S_;
  int T = 100 + 4 * qb;
  int half = T >> 1;
  int t0 = sp ? half : 0;
  int t1 = sp ? T : half;
  int koff[2], voff[2], ldst[2];
  #pragma unroll
  for(int i = 0; i < 2; ++i){
    int L = (w*2 + i)*64 + lane;
    ldst[i] = L * 8;
    int r = L >> 4, c8 = (L & 15) ^ (r & 7);
    koff[i] = r*128 + c8*8;
    int d = L >> 2, sc = (L & 3) ^ (d & 3) ^ ((d >> 2) & 3);
    voff[i] = d*S_ + sc*8;
  }
  {
    const unsigned short* kg = Kg + kb + (long)t0 * (KVB*128);
    const unsigned short* vg = VTg + vb0 + t0 * KVB;
    #pragma unroll
    for(int i = 0; i < 2; ++i){
      gl16(kg + koff[i], &Ks[t0 & 1][ldst[i]]);
      gl16(vg + voff[i], &Vs[t0 & 1][ldst[i]]);
    }
  }
  __syncthreads();

  int lr7 = lr & 7;
  for(int t = t0; t < t1; ++t){
    int cur = t & 1;
    if(t + 1 < t1){
      int s1 = (t + 1) * KVB;
      const unsigned short* kg = Kg + kb + (long)s1 * 128;
      const unsigned short* vg = VTg + vb0 + s1;
      #pragma unroll
      for(int i = 0; i < 2; ++i){
        gl16(kg + koff[i], &Ks[cur^1][ldst[i]]);
        gl16(vg + voff[i], &Vs[cur^1][ldst[i]]);
      }
    }
    int s0 = t * KVB;
    if(s0 <= P_ + q0w + 31){
      // ---- QK^T (swapped: A=K rows=keys, B=Q cols=queries), C seeded with -M ----
      f32x4 pacc[2][2];
      pacc[0][0] = minit; pacc[0][1] = minit; pacc[1][0] = minit; pacc[1][1] = minit;
      #pragma unroll
      for(int c = 0; c < 4; ++c)
        #pragma unroll
        for(int ni = 0; ni < 2; ++ni){
          u16x8 kh = *(const u16x8*)(&Ks[cur][(ni*16 + lr)*128 + (((c*4 + lg) ^ lr7) << 3)]);
          pacc[0][ni] = mfma16(kh, qh[0][c], pacc[0][ni]);
          pacc[1][ni] = mfma16(kh, qh[1][c], pacc[1][ni]);
        }
      // ---- causal mask (lane holds q=lr, keys ni*16+lg*4+r) ----
      if(s0 + KVB - 1 > P_ + q0w){
        #pragma unroll
        for(int mi = 0; mi < 2; ++mi){
          int qrow = q0w + mi*16 + lr;
          #pragma unroll
          for(int ni = 0; ni < 2; ++ni)
            #pragma unroll
            for(int r = 0; r < 4; ++r){
              int skey = s0 + ni*16 + lg*4 + r;
              if(skey > P_ + qrow) pacc[mi][ni][r] = -1e30f;
            }
        }
      }
      // ---- p = exp2(s - M): no max tracking, no rescale, no cross-lane ops ----
      #pragma unroll
      for(int mi = 0; mi < 2; ++mi){
        float rs = 0.f;
        #pragma unroll
        for(int ni = 0; ni < 2; ++ni){
          float p0 = exp2f(pacc[mi][ni][0]);
          float p1 = exp2f(pacc[mi][ni][1]);
          float p2 = exp2f(pacc[mi][ni][2]);
          float p3 = exp2f(pacc[mi][ni][3]);
          rs += (p0 + p1) + (p2 + p3);
          uint2 pw; pw.x = pk2bf(p0, p1); pw.y = pk2bf(p2, p3);
          *(uint2*)(&Ps[w][(mi*16 + lr)*PSL + ni*16 + lg*4]) = pw;
        }
        l[mi] += rs;
      }
      // ---- PV: A = P (rows=q), B = V^T (cols=d) ----
      u16x8 pa0 = *(const u16x8*)(&Ps[w][lr*PSL + lg*8]);
      u16x8 pa1 = *(const u16x8*)(&Ps[w][(16 + lr)*PSL + lg*8]);
      #pragma unroll
      for(int ni = 0; ni < 8; ++ni){
        int d = ni*16 + lr;
        int scs = lg ^ (lr & 3) ^ ((lr >> 2) & 3);
        u16x8 vbf = *(const u16x8*)(&Vs[cur][d*32 + (scs << 3)]);
        o[0][ni] = mfma16(pa0, vbf, o[0][ni]);
        o[1][ni] = mfma16(pa1, vbf, o[1][ni]);
      }
    }
    __syncthreads();
  }
  // ---- epilogue: write partial o (f32) and partial l ----
  int bh = b * H_ + h;
  #pragma unroll
  for(int mi = 0; mi < 2; ++mi){
    float lt = l[mi];
    lt += __shfl_xor(lt, 16);
    lt += __shfl_xor(lt, 32);
    #pragma unroll
    for(int r = 0; r < 4; ++r){
      int qrow = q0w + mi*16 + lg*4 + r;
      long obase = ((long)(sp*64 + bh) * Q_ + qrow) * 128;
      #pragma unroll
      for(int ni = 0; ni < 8; ++ni)
        po[obase + ni*16 + lr] = o[mi][ni][r];
    }
    if(lane < 16)
      pl[(sp*64 + bh) * Q_ + q0w + mi*16 + lane] = lt;
  }
}

// ---------------- combine: OH = (po0 + po1) / (pl0 + pl1), bf16 --------------------------
__global__ __launch_bounds__(256) void combine(
    const float* __restrict__ po, const float* __restrict__ pl,
    unsigned short* __restrict__ OH){
  int idx = blockIdx.x * 256 + threadIdx.x;   // 2,097,152 total
  int row = idx >> 5;
  int d4 = (idx & 31) * 4;
  int bh = row >> 10, q = row & 1023;
  int b = bh >> 5, h = bh & 31;
  float lsum = pl[bh*1024 + q] + pl[65536 + bh*1024 + q];
  float inv = 1.0f / lsum;
  float4 a = *(const float4*)(po + (long)row*128 + d4);
  float4 c = *(const float4*)(po + 8388608L + (long)row*128 + d4);
  u16x4 r = { f2bf((a.x + c.x) * inv), f2bf((a.y + c.y) * inv),
              f2bf((a.z + c.z) * inv), f2bf((a.w + c.w) * inv) };
  *(u16x4*)(OH + ((long)(b*1024 + q))*4096 + h*128 + d4) = r;
}

extern "C" void kernel_launch(void* const* d_in, const int* in_sizes, int n_in,
                              void* d_out, int out_size, void* d_ws, size_t ws_size,
                              hipStream_t stream){
  const float* hs   = (const float*)d_in[0];
  const float* cosb = (const float*)d_in[1];
  const float* sinb = (const float*)d_in[2];
  const float* kc   = (const float*)d_in[3];
  const float* vc   = (const float*)d_in[4];
  const float* Wq   = (const float*)d_in[5];
  const float* Wk   = (const float*)d_in[6];
  const float* Wv   = (const float*)d_in[7];
  const float* Wo   = (const float*)d_in[8];
  const float* qw   = (const float*)d_in[9];
  const float* kw   = (const float*)d_in[10];
  char* ws = (char*)d_ws;
  // layout: [0,50.3M) Craw (dead after pp_*) -> OH@0 (16.7M), PL@16.7M, MW@17.3M
  //         [50.3M,150.9M) WT 6144x4096 bf16 -> WoTh@50.3M (33.5M), PO@83.9M (64MiB)
  //         [151.0M,167.8M) AH -> QB ; [184.5M..) KB ; [218.1M..) VT
  float* Craw          = (float*)ws;
  unsigned short* OH   = (unsigned short*)ws;
  float* PL            = (float*)(ws + 16777216);
  float* MW            = (float*)(ws + 17301504);
  unsigned short* WTh  = (unsigned short*)(ws + 50331648);
  unsigned short* WoTh = (unsigned short*)(ws + 50331648);
  float* PO            = (float*)(ws + 83886080);
  unsigned short* AH   = (unsigned short*)(ws + 150994944);
  unsigned short* QB   = (unsigned short*)(ws + 150994944);
  unsigned short* KB   = (unsigned short*)(ws + 184549376);
  unsigned short* VT   = (unsigned short*)(ws + 218103808);
  float* Out = (float*)d_out;

  convert_hs<<<dim3(2048), dim3(256), 0, stream>>>(hs, AH, (B_*Q_*HID_)/4);
  convert_wt<<<dim3(64,64), dim3(256), 0, stream>>>(Wq, WTh, 4096, 0);
  convert_wt<<<dim3(16,64), dim3(256), 0, stream>>>(Wk, WTh, 1024, 4096);
  convert_wt<<<dim3(16,64), dim3(256), 0, stream>>>(Wv, WTh, 1024, 5120);
  cache_k<<<dim3(2048), dim3(256), 0, stream>>>(kc, KB);
  cache_vt<<<dim3(48, 16), dim3(256), 0, stream>>>(vc, VT);
  gemm_bf16<<<dim3(768), dim3(256), 0, stream>>>(AH, WTh, Craw, 48, NQKV);
  pp_q<<<dim3(16384), dim3(256), 0, stream>>>(Craw, cosb, sinb, qw, QB);
  pp_kv<<<dim3(4096), dim3(256), 0, stream>>>(Craw, cosb, sinb, kw, KB, VT);
  maxw<<<dim3(1), dim3(128), 0, stream>>>(qw, kw, MW);
  convert_wt<<<dim3(64,64), dim3(256), 0, stream>>>(Wo, WoTh, 4096, 0);
  attn<<<dim3(16, 32, 2), dim3(256), 0, stream>>>(QB, KB, VT, MW, PO, PL);
  combine<<<dim3(8192), dim3(256), 0, stream>>>(PO, PL, OH);
  gemm_bf16<<<dim3(512), dim3(256), 0, stream>>>(OH, WoTh, Out, 32, 4096);
}